// Round 5
// baseline (2830.244 us; speedup 1.0000x reference)
//
#include <hip/hip_runtime.h>
#include <hip/hip_bf16.h>
#include <math.h>

#define BB 4
#define TT 1024
#define DD 1024
#define HH 16
#define HDIM 64
#define FFD 4096
#define VV 32000
#define LL 6
#define BT (BB * TT)

typedef __bf16 bf16;
typedef bf16 bf16x8 __attribute__((ext_vector_type(8)));
typedef bf16 bf16x4 __attribute__((ext_vector_type(4)));
typedef float f32x4 __attribute__((ext_vector_type(4)));

__device__ __forceinline__ void gload16(const void* g, void* l) {
    __builtin_amdgcn_global_load_lds((__attribute__((address_space(1))) unsigned int*)(g),
                                     (__attribute__((address_space(3))) unsigned int*)(l),
                                     16, 0, 0);
}

// ---------------- embedding ----------------
__global__ __launch_bounds__(256) void embed_k(const int* __restrict__ idx,
                                               const float* __restrict__ tok,
                                               const float* __restrict__ pos,
                                               float* __restrict__ x) {
    int row = blockIdx.x;
    int tid = threadIdx.x;
    int t = row & (TT - 1);
    int token = idx[row];
    float4 a = *(const float4*)(tok + (size_t)token * DD + tid * 4);
    float4 p = *(const float4*)(pos + (size_t)t * DD + tid * 4);
    *(float4*)(x + (size_t)row * DD + tid * 4) =
        make_float4(a.x + p.x, a.y + p.y, a.z + p.z, a.w + p.w);
}

// ---------------- f32 -> bf16 conversion (weights) ----------------
__global__ __launch_bounds__(256) void cvt_bf16_k(const float* __restrict__ in,
                                                  bf16* __restrict__ out, long n) {
    long i0 = ((long)blockIdx.x * 256 + threadIdx.x) * 8;
    long stride = (long)gridDim.x * 256 * 8;
    for (long i = i0; i < n; i += stride) {
        float4 v0 = *(const float4*)(in + i);
        float4 v1 = *(const float4*)(in + i + 4);
        bf16x8 o;
        o[0] = (bf16)v0.x; o[1] = (bf16)v0.y; o[2] = (bf16)v0.z; o[3] = (bf16)v0.w;
        o[4] = (bf16)v1.x; o[5] = (bf16)v1.y; o[6] = (bf16)v1.z; o[7] = (bf16)v1.w;
        *(bf16x8*)(out + i) = o;
    }
}

// ---------------- layernorm: f32 in, bf16 out ----------------
__global__ __launch_bounds__(256) void layernorm_k(const float* __restrict__ in,
                                                   bf16* __restrict__ out,
                                                   const float* __restrict__ g,
                                                   const float* __restrict__ b) {
    __shared__ float red[256];
    int row = blockIdx.x;
    int tid = threadIdx.x;
    const float* ip = in + (size_t)row * DD;
    float4 v = *(const float4*)(ip + tid * 4);

    float s = v.x + v.y + v.z + v.w;
    red[tid] = s; __syncthreads();
    for (int st = 128; st > 0; st >>= 1) { if (tid < st) red[tid] += red[tid + st]; __syncthreads(); }
    float mu = red[0] * (1.0f / DD);
    __syncthreads();

    float d0 = v.x - mu, d1 = v.y - mu, d2 = v.z - mu, d3 = v.w - mu;
    red[tid] = d0 * d0 + d1 * d1 + d2 * d2 + d3 * d3; __syncthreads();
    for (int st = 128; st > 0; st >>= 1) { if (tid < st) red[tid] += red[tid + st]; __syncthreads(); }
    float var = red[0] * (1.0f / DD);
    float rs = rsqrtf(var + 1e-5f);

    float4 gv = *(const float4*)(g + tid * 4);
    float4 bv = *(const float4*)(b + tid * 4);
    bf16x4 o;
    o[0] = (bf16)(d0 * rs * gv.x + bv.x);
    o[1] = (bf16)(d1 * rs * gv.y + bv.y);
    o[2] = (bf16)(d2 * rs * gv.z + bv.z);
    o[3] = (bf16)(d3 * rs * gv.w + bv.w);
    *(bf16x4*)(out + (size_t)row * DD + tid * 4) = o;
}

// ---------------- bf16 MFMA GEMM: C[M,N] (=/+=) A[M,K] * W[N,K]^T ----------------
// 1D grid = (M/128)*(N/128); M-tile fastest (blocks sharing a W panel are
// consecutive -> W fetched ~once, A L3-resident), bijective XCD swizzle (m204).
template <bool ADD, bool BIAS, bool GELU, bool OBF>
__global__ __launch_bounds__(256) void gemm_mfma(const bf16* __restrict__ A,
                                                 const bf16* __restrict__ W,
                                                 const float* __restrict__ bias,
                                                 void* __restrict__ Cv,
                                                 int M, int N, int K) {
    __shared__ bf16 As[128 * 32];
    __shared__ bf16 Ws[128 * 32];
    const int tid  = threadIdx.x;
    const int wave = tid >> 6, lane = tid & 63;

    const int nm = M >> 7;
    const int nwg = gridDim.x;
    const int qc = nwg >> 3, rc = nwg & 7;
    const int xcd = blockIdx.x & 7, lid = blockIdx.x >> 3;
    const int wgid = (xcd < rc ? xcd * (qc + 1) : rc * (qc + 1) + (xcd - rc) * qc) + lid;
    const int m0 = (wgid % nm) * 128, n0 = (wgid / nm) * 128;

    const int wm = (wave >> 1) * 64, wn = (wave & 1) * 64;

    const int srow = wave * 16 + (lane >> 2);
    const int sk   = (lane & 3) * 8;
    const bf16* Ag = A + (size_t)(m0 + srow) * K + sk;
    const bf16* Wg = W + (size_t)(n0 + srow) * K + sk;
    char* lA = (char*)As + wave * 1024;
    char* lW = (char*)Ws + wave * 1024;

    const int rl = lane & 15, kg = lane >> 4;
    const bf16* Ard = As + (size_t)(wm + rl) * 32 + kg * 8;
    const bf16* Wrd = Ws + (size_t)(wn + rl) * 32 + kg * 8;

    f32x4 acc[4][4] = {};

    for (int k0 = 0; k0 < K; k0 += 32) {
        gload16(Ag + k0,                   lA);
        gload16(Ag + k0 + (size_t)64 * K,  lA + 4096);
        gload16(Wg + k0,                   lW);
        gload16(Wg + k0 + (size_t)64 * K,  lW + 4096);
        __syncthreads();
        bf16x8 a[4], b[4];
#pragma unroll
        for (int i = 0; i < 4; ++i) a[i] = *(const bf16x8*)(Ard + i * 16 * 32);
#pragma unroll
        for (int j = 0; j < 4; ++j) b[j] = *(const bf16x8*)(Wrd + j * 16 * 32);
#pragma unroll
        for (int i = 0; i < 4; ++i)
#pragma unroll
            for (int j = 0; j < 4; ++j)
                acc[i][j] = __builtin_amdgcn_mfma_f32_16x16x32_bf16(a[i], b[j], acc[i][j], 0, 0, 0);
        __syncthreads();
    }

    const int orow  = m0 + wm + (lane >> 4) * 4;
    const int ocol0 = n0 + wn + (lane & 15);
#pragma unroll
    for (int j = 0; j < 4; ++j) {
        const int col = ocol0 + j * 16;
        float bs = 0.f;
        if (BIAS) bs = bias[col];
#pragma unroll
        for (int i = 0; i < 4; ++i) {
#pragma unroll
            for (int r = 0; r < 4; ++r) {
                int row = orow + i * 16 + r;
                float v = acc[i][j][r] + bs;
                if (GELU) v = 0.5f * v * (1.0f + erff(v * 0.70710678118654752f));
                if (OBF) {
                    ((bf16*)Cv)[(size_t)row * N + col] = (bf16)v;
                } else {
                    float* p = (float*)Cv + (size_t)row * N + col;
                    if (ADD) *p += v; else *p = v;
                }
            }
        }
    }
}

// ---------------- V transpose+swizzle prep: Vt[b,h,d,t] from qkv_bf ----------------
__global__ __launch_bounds__(256) void vprep_k(const bf16* __restrict__ qkv,
                                               bf16* __restrict__ Vt) {
    int tid = blockIdx.x * 256 + threadIdx.x;   // B*H*64*128 = 524288
    int q  = tid & 127;
    int d  = (tid >> 7) & 63;
    int bh = tid >> 13;
    int b = bh >> 4, h = bh & 15;
    int sw = (d ^ (d >> 2)) & 3;
    int srcc = (q & ~3) | ((q & 3) ^ sw);
    const bf16* src = qkv + ((size_t)(b * TT + srcc * 8)) * 3072 + 2048 + h * 64 + d;
    bf16x8 v;
#pragma unroll
    for (int i = 0; i < 8; ++i) v[i] = src[(size_t)i * 3072];
    *(bf16x8*)(Vt + ((size_t)bh * 64 + d) * 1024 + q * 8) = v;
}

// ---------------- flash attention: block = (qtile 64, h, b), 4 waves x 16 q-rows ----------------
__global__ __launch_bounds__(256) void fattn_k(const bf16* __restrict__ qkv,
                                               const bf16* __restrict__ Vt,
                                               bf16* __restrict__ y) {
    __shared__ bf16 Ks[32 * 64];
    __shared__ bf16 Vs[64 * 32];
    __shared__ bf16 Ps[4 * 640];
    const int tid = threadIdx.x, lane = tid & 63, wave = tid >> 6;
    const int g = lane >> 4, c = lane & 15;
    const int q0 = blockIdx.x * 64;
    const int h = blockIdx.y, b = blockIdx.z;
    const size_t qbase = (size_t)b * TT * 3072;

    const int qrow = q0 + wave * 16 + c;
    const bf16* qp = qkv + qbase + (size_t)qrow * 3072 + h * 64;
    bf16x8 qf0 = *(const bf16x8*)(qp + g * 8);
    bf16x8 qf1 = *(const bf16x8*)(qp + 32 + g * 8);

    const int skrow = tid >> 3, skp = tid & 7;
    const size_t koff = qbase + 1024 + h * 64 + ((skp ^ (skrow & 7)) * 8);
    const int svd = tid >> 2, svp = tid & 3;
    const size_t vtbase = ((size_t)(b * HH + h) * 64 + svd) * 1024 + svp * 8;

    float mO[4] = {-1e30f, -1e30f, -1e30f, -1e30f};
    float lO[4] = {0.f, 0.f, 0.f, 0.f};
    f32x4 acc[4] = {};

    bf16* pw = Ps + wave * 640;
    const int kend = q0 + 64;
    const int qg0 = q0 + wave * 16 + 4 * g;

    for (int k0 = 0; k0 < kend; k0 += 32) {
        gload16(qkv + koff + (size_t)(k0 + skrow) * 3072, (char*)Ks + tid * 16);
        gload16(Vt + vtbase + k0, (char*)Vs + tid * 16);
        __syncthreads();

        const int cw = c & 7;
        bf16x8 kf00 = *(const bf16x8*)(Ks + c * 64        + ((g ^ cw) * 8));
        bf16x8 kf01 = *(const bf16x8*)(Ks + c * 64        + (((4 + g) ^ cw) * 8));
        bf16x8 kf10 = *(const bf16x8*)(Ks + (16 + c) * 64 + ((g ^ cw) * 8));
        bf16x8 kf11 = *(const bf16x8*)(Ks + (16 + c) * 64 + (((4 + g) ^ cw) * 8));
        f32x4 s0 = {}, s1 = {};
        s0 = __builtin_amdgcn_mfma_f32_16x16x32_bf16(qf0, kf00, s0, 0, 0, 0);
        s0 = __builtin_amdgcn_mfma_f32_16x16x32_bf16(qf1, kf01, s0, 0, 0, 0);
        s1 = __builtin_amdgcn_mfma_f32_16x16x32_bf16(qf0, kf10, s1, 0, 0, 0);
        s1 = __builtin_amdgcn_mfma_f32_16x16x32_bf16(qf1, kf11, s1, 0, 0, 0);

#pragma unroll
        for (int r = 0; r < 4; ++r) {
            float a  = s0[r] * 0.125f;
            float bv = s1[r] * 0.125f;
            int qg = qg0 + r;
            if (k0 + c > qg)      a  = -1e30f;
            if (k0 + 16 + c > qg) bv = -1e30f;
            float mt = fmaxf(a, bv);
            mt = fmaxf(mt, __shfl_xor(mt, 1));
            mt = fmaxf(mt, __shfl_xor(mt, 2));
            mt = fmaxf(mt, __shfl_xor(mt, 4));
            mt = fmaxf(mt, __shfl_xor(mt, 8));
            float mn = fmaxf(mO[r], mt);
            float sc = __expf(mO[r] - mn);
            mO[r] = mn;
            float e0 = __expf(a - mn), e1 = __expf(bv - mn);
            float rs = e0 + e1;
            rs += __shfl_xor(rs, 1);
            rs += __shfl_xor(rs, 2);
            rs += __shfl_xor(rs, 4);
            rs += __shfl_xor(rs, 8);
            lO[r] = lO[r] * sc + rs;
            acc[0][r] *= sc; acc[1][r] *= sc; acc[2][r] *= sc; acc[3][r] *= sc;
            pw[(4 * g + r) * 40 + c]      = (bf16)e0;
            pw[(4 * g + r) * 40 + 16 + c] = (bf16)e1;
        }

        bf16x8 pf = *(const bf16x8*)(pw + c * 40 + g * 8);
#pragma unroll
        for (int jb = 0; jb < 4; ++jb) {
            int d = jb * 16 + c;
            int swd = (d ^ (d >> 2)) & 3;
            bf16x8 vf = *(const bf16x8*)(Vs + d * 32 + ((g ^ swd) * 8));
            acc[jb] = __builtin_amdgcn_mfma_f32_16x16x32_bf16(pf, vf, acc[jb], 0, 0, 0);
        }
        __syncthreads();
    }

#pragma unroll
    for (int r = 0; r < 4; ++r) {
        float invl = 1.0f / lO[r];
        size_t orow = (size_t)(b * TT + qg0 + r) * DD + h * 64;
#pragma unroll
        for (int jb = 0; jb < 4; ++jb)
            y[orow + jb * 16 + c] = (bf16)(acc[jb][r] * invl);
    }
}

// ---------------- host ----------------
extern "C" void kernel_launch(void* const* d_in, const int* in_sizes, int n_in,
                              void* d_out, int out_size, void* d_ws, size_t ws_size,
                              hipStream_t stream) {
    const int*   idx     = (const int*)d_in[0];
    const float* tok_emb = (const float*)d_in[1];
    const float* pos_emb = (const float*)d_in[2];
    const float* ln1_g   = (const float*)d_in[3];
    const float* ln1_b   = (const float*)d_in[4];
    const float* qkv_w   = (const float*)d_in[5];
    const float* proj_w  = (const float*)d_in[6];
    const float* ln2_g   = (const float*)d_in[7];
    const float* ln2_b   = (const float*)d_in[8];
    const float* mlp_w1  = (const float*)d_in[9];
    const float* mlp_b1  = (const float*)d_in[10];
    const float* mlp_w2  = (const float*)d_in[11];
    const float* mlp_b2  = (const float*)d_in[12];
    const float* lnf_g   = (const float*)d_in[13];
    const float* lnf_b   = (const float*)d_in[14];
    const float* head_w  = (const float*)d_in[15];
    float* out = (float*)d_out;

    char* ws = (char*)d_ws;
    float* x      = (float*)ws;
    bf16*  qkv_bf = (bf16*)(ws + (16ull << 20));
    bf16*  Vt     = (bf16*)(ws + (40ull << 20));
    bf16*  h_bf   = (bf16*)(ws + (48ull << 20));
    bf16*  y_bf   = (bf16*)(ws + (56ull << 20));
    bf16*  ff_bf  = (bf16*)(ws + (64ull << 20));
    bf16*  wbuf   = (bf16*)(ws + (96ull << 20));
    bf16*  hw_bf  = (bf16*)(ws + (56ull << 20));

    embed_k<<<BT, 256, 0, stream>>>(idx, tok_emb, pos_emb, x);

    for (int l = 0; l < LL; ++l) {
        layernorm_k<<<BT, 256, 0, stream>>>(x, h_bf, ln1_g + (size_t)l * DD, ln1_b + (size_t)l * DD);
        cvt_bf16_k<<<2048, 256, 0, stream>>>(qkv_w + (size_t)l * 3 * DD * DD, wbuf, (long)3 * DD * DD);
        gemm_mfma<false, false, false, true><<<(BT / 128) * (3 * DD / 128), 256, 0, stream>>>(
            h_bf, wbuf, nullptr, qkv_bf, BT, 3 * DD, DD);
        vprep_k<<<2048, 256, 0, stream>>>(qkv_bf, Vt);
        fattn_k<<<dim3(TT / 64, HH, BB), 256, 0, stream>>>(qkv_bf, Vt, y_bf);
        cvt_bf16_k<<<2048, 256, 0, stream>>>(proj_w + (size_t)l * DD * DD, wbuf, (long)DD * DD);
        gemm_mfma<true, false, false, false><<<(BT / 128) * (DD / 128), 256, 0, stream>>>(
            y_bf, wbuf, nullptr, x, BT, DD, DD);
        layernorm_k<<<BT, 256, 0, stream>>>(x, h_bf, ln2_g + (size_t)l * DD, ln2_b + (size_t)l * DD);
        cvt_bf16_k<<<2048, 256, 0, stream>>>(mlp_w1 + (size_t)l * FFD * DD, wbuf, (long)FFD * DD);
        gemm_mfma<false, true, true, true><<<(BT / 128) * (FFD / 128), 256, 0, stream>>>(
            h_bf, wbuf, mlp_b1 + (size_t)l * FFD, ff_bf, BT, FFD, DD);
        cvt_bf16_k<<<2048, 256, 0, stream>>>(mlp_w2 + (size_t)l * DD * FFD, wbuf, (long)DD * FFD);
        gemm_mfma<true, true, false, false><<<(BT / 128) * (DD / 128), 256, 0, stream>>>(
            ff_bf, wbuf, mlp_b2 + (size_t)l * DD, x, BT, DD, FFD);
    }

    layernorm_k<<<BT, 256, 0, stream>>>(x, h_bf, lnf_g, lnf_b);
    cvt_bf16_k<<<4096, 256, 0, stream>>>(head_w, hw_bf, (long)VV * DD);
    gemm_mfma<false, false, false, false><<<(BT / 128) * (VV / 128), 256, 0, stream>>>(
        h_bf, hw_bf, nullptr, out, BT, VV, DD);
}

// Round 6
// 2739.415 us; speedup vs baseline: 1.0332x; 1.0332x over previous
//
#include <hip/hip_runtime.h>
#include <hip/hip_bf16.h>
#include <math.h>

#define BB 4
#define TT 1024
#define DD 1024
#define HH 16
#define HDIM 64
#define FFD 4096
#define VV 32000
#define LL 6
#define BT (BB * TT)

typedef __bf16 bf16;
typedef bf16 bf16x8 __attribute__((ext_vector_type(8)));
typedef bf16 bf16x4 __attribute__((ext_vector_type(4)));
typedef float f32x4 __attribute__((ext_vector_type(4)));

__device__ __forceinline__ void gload16(const void* g, void* l) {
    __builtin_amdgcn_global_load_lds((__attribute__((address_space(1))) unsigned int*)(g),
                                     (__attribute__((address_space(3))) unsigned int*)(l),
                                     16, 0, 0);
}

// ---------------- embedding ----------------
__global__ __launch_bounds__(256) void embed_k(const int* __restrict__ idx,
                                               const float* __restrict__ tok,
                                               const float* __restrict__ pos,
                                               float* __restrict__ x) {
    int row = blockIdx.x;
    int tid = threadIdx.x;
    int t = row & (TT - 1);
    int token = idx[row];
    float4 a = *(const float4*)(tok + (size_t)token * DD + tid * 4);
    float4 p = *(const float4*)(pos + (size_t)t * DD + tid * 4);
    *(float4*)(x + (size_t)row * DD + tid * 4) =
        make_float4(a.x + p.x, a.y + p.y, a.z + p.z, a.w + p.w);
}

// ---------------- f32 -> bf16 conversion (weights) ----------------
__global__ __launch_bounds__(256) void cvt_bf16_k(const float* __restrict__ in,
                                                  bf16* __restrict__ out, long n) {
    long i0 = ((long)blockIdx.x * 256 + threadIdx.x) * 8;
    long stride = (long)gridDim.x * 256 * 8;
    for (long i = i0; i < n; i += stride) {
        float4 v0 = *(const float4*)(in + i);
        float4 v1 = *(const float4*)(in + i + 4);
        bf16x8 o;
        o[0] = (bf16)v0.x; o[1] = (bf16)v0.y; o[2] = (bf16)v0.z; o[3] = (bf16)v0.w;
        o[4] = (bf16)v1.x; o[5] = (bf16)v1.y; o[6] = (bf16)v1.z; o[7] = (bf16)v1.w;
        *(bf16x8*)(out + i) = o;
    }
}

// ---------------- layernorm: f32 in, bf16 out ----------------
__global__ __launch_bounds__(256) void layernorm_k(const float* __restrict__ in,
                                                   bf16* __restrict__ out,
                                                   const float* __restrict__ g,
                                                   const float* __restrict__ b) {
    __shared__ float red[256];
    int row = blockIdx.x;
    int tid = threadIdx.x;
    const float* ip = in + (size_t)row * DD;
    float4 v = *(const float4*)(ip + tid * 4);

    float s = v.x + v.y + v.z + v.w;
    red[tid] = s; __syncthreads();
    for (int st = 128; st > 0; st >>= 1) { if (tid < st) red[tid] += red[tid + st]; __syncthreads(); }
    float mu = red[0] * (1.0f / DD);
    __syncthreads();

    float d0 = v.x - mu, d1 = v.y - mu, d2 = v.z - mu, d3 = v.w - mu;
    red[tid] = d0 * d0 + d1 * d1 + d2 * d2 + d3 * d3; __syncthreads();
    for (int st = 128; st > 0; st >>= 1) { if (tid < st) red[tid] += red[tid + st]; __syncthreads(); }
    float var = red[0] * (1.0f / DD);
    float rs = rsqrtf(var + 1e-5f);

    float4 gv = *(const float4*)(g + tid * 4);
    float4 bv = *(const float4*)(b + tid * 4);
    bf16x4 o;
    o[0] = (bf16)(d0 * rs * gv.x + bv.x);
    o[1] = (bf16)(d1 * rs * gv.y + bv.y);
    o[2] = (bf16)(d2 * rs * gv.z + bv.z);
    o[3] = (bf16)(d3 * rs * gv.w + bv.w);
    *(bf16x4*)(out + (size_t)row * DD + tid * 4) = o;
}

// ======== big-N GEMM: BM=256 x BN=128, BK=64, 512 thr, 3-buf deep pipeline ========
// C[M,N] = A[M,K] * W[N,K]^T ; counted vmcnt (12/6/0), XOR-swizzled LDS,
// setprio around MFMA, 2 raw barriers per K-tile (no drain).
template <bool BIAS, bool GELU, bool OBF>
__global__ __launch_bounds__(512) void gemm_big(const bf16* __restrict__ A,
                                                const bf16* __restrict__ W,
                                                const float* __restrict__ bias,
                                                void* __restrict__ Cv,
                                                int M, int N, int K) {
    __shared__ char lds[3 * 49152];      // per buf: A 32KB @0, B 16KB @32768
    const int tid = threadIdx.x;
    const int lane = tid & 63, wave = tid >> 6;
    const int c = lane & 15, g = lane >> 4;

    // 1-D grid, bijective XCD remap (grid%8==0), M-fastest
    const int nm = M >> 8;
    const int nwg = gridDim.x;
    const int wgid = (blockIdx.x & 7) * (nwg >> 3) + (blockIdx.x >> 3);
    const int m0 = (wgid % nm) * 256, n0 = (wgid / nm) * 128;

    const int wm = wave >> 1, wn = wave & 1;       // 4 x 2 waves, 64x64 each
    const int wmB = wm * 64, wnB = wn * 64;

    // staging: thread stages row (tid>>3)+i*64, swizzled k-chunk ck
    const int ck = (tid & 7) ^ ((tid >> 3) & 7);
    const size_t aoff = (size_t)(m0 + (tid >> 3)) * K + ck * 8;
    const size_t boff = (size_t)(n0 + (tid >> 3)) * K + ck * 8;
    const size_t K64 = (size_t)64 * K;

    // ds-read lane offsets (swizzle: chunk = (kk*4+g) ^ (c&7))
    const int cs = c & 7;
    const int laneK0 = c * 128 + ((g ^ cs) * 16);
    const int laneK1 = c * 128 + (((g ^ cs) ^ 4) * 16);

    f32x4 acc[4][4] = {};

    const int NT = K >> 6;

#define STAGE_BIG(t2, buf)                                                    \
    {                                                                         \
        const size_t k0s = (size_t)(t2) << 6;                                 \
        const bf16* As_ = A + aoff + k0s;                                     \
        char* dA = lds + (buf) * 49152 + tid * 16;                            \
        gload16(As_,            dA);                                          \
        gload16(As_ + K64,      dA + 8192);                                   \
        gload16(As_ + 2 * K64,  dA + 16384);                                  \
        gload16(As_ + 3 * K64,  dA + 24576);                                  \
        const bf16* Bs_ = W + boff + k0s;                                     \
        char* dB = lds + (buf) * 49152 + 32768 + tid * 16;                    \
        gload16(Bs_,            dB);                                          \
        gload16(Bs_ + K64,      dB + 8192);                                   \
    }

    STAGE_BIG(0, 0);
    STAGE_BIG(1, 1);

    for (int t = 0; t < NT; ++t) {
        __builtin_amdgcn_s_barrier();            // all waves done reading buf (t-1)%3
        if (t + 2 < NT) STAGE_BIG(t + 2, (t + 2) % 3);
        if (t + 2 < NT) {
            asm volatile("s_waitcnt vmcnt(12)" ::: "memory");
        } else if (t + 1 < NT) {
            asm volatile("s_waitcnt vmcnt(6)" ::: "memory");
        } else {
            asm volatile("s_waitcnt vmcnt(0)" ::: "memory");
        }
        __builtin_amdgcn_sched_barrier(0);
        __builtin_amdgcn_s_barrier();            // tile t resident for all waves

        const char* bufp = lds + (t % 3) * 49152;
        {   // kk = 0
            bf16x8 av[4], bv[4];
#pragma unroll
            for (int fi = 0; fi < 4; ++fi)
                av[fi] = *(const bf16x8*)(bufp + laneK0 + (wmB + fi * 16) * 128);
#pragma unroll
            for (int fj = 0; fj < 4; ++fj)
                bv[fj] = *(const bf16x8*)(bufp + 32768 + laneK0 + (wnB + fj * 16) * 128);
            __builtin_amdgcn_s_setprio(1);
#pragma unroll
            for (int fi = 0; fi < 4; ++fi)
#pragma unroll
                for (int fj = 0; fj < 4; ++fj)
                    acc[fi][fj] = __builtin_amdgcn_mfma_f32_16x16x32_bf16(av[fi], bv[fj], acc[fi][fj], 0, 0, 0);
            __builtin_amdgcn_s_setprio(0);
        }
        {   // kk = 1
            bf16x8 av[4], bv[4];
#pragma unroll
            for (int fi = 0; fi < 4; ++fi)
                av[fi] = *(const bf16x8*)(bufp + laneK1 + (wmB + fi * 16) * 128);
#pragma unroll
            for (int fj = 0; fj < 4; ++fj)
                bv[fj] = *(const bf16x8*)(bufp + 32768 + laneK1 + (wnB + fj * 16) * 128);
            __builtin_amdgcn_s_setprio(1);
#pragma unroll
            for (int fi = 0; fi < 4; ++fi)
#pragma unroll
                for (int fj = 0; fj < 4; ++fj)
                    acc[fi][fj] = __builtin_amdgcn_mfma_f32_16x16x32_bf16(av[fi], bv[fj], acc[fi][fj], 0, 0, 0);
            __builtin_amdgcn_s_setprio(0);
        }
    }
#undef STAGE_BIG

    const int orow  = m0 + wmB + g * 4;
    const int ocol0 = n0 + wnB + c;
#pragma unroll
    for (int fj = 0; fj < 4; ++fj) {
        const int col = ocol0 + fj * 16;
        float bs = 0.f;
        if (BIAS) bs = bias[col];
#pragma unroll
        for (int fi = 0; fi < 4; ++fi) {
#pragma unroll
            for (int r = 0; r < 4; ++r) {
                int row = orow + fi * 16 + r;
                float v = acc[fi][fj][r] + bs;
                if (GELU) v = 0.5f * v * (1.0f + erff(v * 0.70710678118654752f));
                if (OBF) ((bf16*)Cv)[(size_t)row * N + col] = (bf16)v;
                else     ((float*)Cv)[(size_t)row * N + col] = v;
            }
        }
    }
}

// ---------------- 128x128 MFMA GEMM (kept for N=1024 shapes) ----------------
template <bool ADD, bool BIAS, bool GELU, bool OBF>
__global__ __launch_bounds__(256) void gemm_mfma(const bf16* __restrict__ A,
                                                 const bf16* __restrict__ W,
                                                 const float* __restrict__ bias,
                                                 void* __restrict__ Cv,
                                                 int M, int N, int K) {
    __shared__ bf16 As[128 * 32];
    __shared__ bf16 Ws[128 * 32];
    const int tid  = threadIdx.x;
    const int wave = tid >> 6, lane = tid & 63;

    const int nm = M >> 7;
    const int nwg = gridDim.x;
    const int wgid = (blockIdx.x & 7) * (nwg >> 3) + (blockIdx.x >> 3);
    const int m0 = (wgid % nm) * 128, n0 = (wgid / nm) * 128;

    const int wm = (wave >> 1) * 64, wn = (wave & 1) * 64;

    const int srow = wave * 16 + (lane >> 2);
    const int sk   = (lane & 3) * 8;
    const bf16* Ag = A + (size_t)(m0 + srow) * K + sk;
    const bf16* Wg = W + (size_t)(n0 + srow) * K + sk;
    char* lA = (char*)As + wave * 1024;
    char* lW = (char*)Ws + wave * 1024;

    const int rl = lane & 15, kg = lane >> 4;
    const bf16* Ard = As + (size_t)(wm + rl) * 32 + kg * 8;
    const bf16* Wrd = Ws + (size_t)(wn + rl) * 32 + kg * 8;

    f32x4 acc[4][4] = {};

    for (int k0 = 0; k0 < K; k0 += 32) {
        gload16(Ag + k0,                   lA);
        gload16(Ag + k0 + (size_t)64 * K,  lA + 4096);
        gload16(Wg + k0,                   lW);
        gload16(Wg + k0 + (size_t)64 * K,  lW + 4096);
        __syncthreads();
        bf16x8 a[4], b[4];
#pragma unroll
        for (int i = 0; i < 4; ++i) a[i] = *(const bf16x8*)(Ard + i * 16 * 32);
#pragma unroll
        for (int j = 0; j < 4; ++j) b[j] = *(const bf16x8*)(Wrd + j * 16 * 32);
#pragma unroll
        for (int i = 0; i < 4; ++i)
#pragma unroll
            for (int j = 0; j < 4; ++j)
                acc[i][j] = __builtin_amdgcn_mfma_f32_16x16x32_bf16(a[i], b[j], acc[i][j], 0, 0, 0);
        __syncthreads();
    }

    const int orow  = m0 + wm + (lane >> 4) * 4;
    const int ocol0 = n0 + wn + (lane & 15);
#pragma unroll
    for (int j = 0; j < 4; ++j) {
        const int col = ocol0 + j * 16;
        float bs = 0.f;
        if (BIAS) bs = bias[col];
#pragma unroll
        for (int i = 0; i < 4; ++i) {
#pragma unroll
            for (int r = 0; r < 4; ++r) {
                int row = orow + i * 16 + r;
                float v = acc[i][j][r] + bs;
                if (GELU) v = 0.5f * v * (1.0f + erff(v * 0.70710678118654752f));
                if (OBF) {
                    ((bf16*)Cv)[(size_t)row * N + col] = (bf16)v;
                } else {
                    float* p = (float*)Cv + (size_t)row * N + col;
                    if (ADD) *p += v; else *p = v;
                }
            }
        }
    }
}

// ---------------- V transpose+swizzle prep ----------------
__global__ __launch_bounds__(256) void vprep_k(const bf16* __restrict__ qkv,
                                               bf16* __restrict__ Vt) {
    int tid = blockIdx.x * 256 + threadIdx.x;
    int q  = tid & 127;
    int d  = (tid >> 7) & 63;
    int bh = tid >> 13;
    int b = bh >> 4, h = bh & 15;
    int sw = (d ^ (d >> 2)) & 3;
    int srcc = (q & ~3) | ((q & 3) ^ sw);
    const bf16* src = qkv + ((size_t)(b * TT + srcc * 8)) * 3072 + 2048 + h * 64 + d;
    bf16x8 v;
#pragma unroll
    for (int i = 0; i < 8; ++i) v[i] = src[(size_t)i * 3072];
    *(bf16x8*)(Vt + ((size_t)bh * 64 + d) * 1024 + q * 8) = v;
}

// ---------------- flash attention ----------------
__global__ __launch_bounds__(256) void fattn_k(const bf16* __restrict__ qkv,
                                               const bf16* __restrict__ Vt,
                                               bf16* __restrict__ y) {
    __shared__ bf16 Ks[32 * 64];
    __shared__ bf16 Vs[64 * 32];
    __shared__ bf16 Ps[4 * 640];
    const int tid = threadIdx.x, lane = tid & 63, wave = tid >> 6;
    const int g = lane >> 4, c = lane & 15;
    const int q0 = blockIdx.x * 64;
    const int h = blockIdx.y, b = blockIdx.z;
    const size_t qbase = (size_t)b * TT * 3072;

    const int qrow = q0 + wave * 16 + c;
    const bf16* qp = qkv + qbase + (size_t)qrow * 3072 + h * 64;
    bf16x8 qf0 = *(const bf16x8*)(qp + g * 8);
    bf16x8 qf1 = *(const bf16x8*)(qp + 32 + g * 8);

    const int skrow = tid >> 3, skp = tid & 7;
    const size_t koff = qbase + 1024 + h * 64 + ((skp ^ (skrow & 7)) * 8);
    const int svd = tid >> 2, svp = tid & 3;
    const size_t vtbase = ((size_t)(b * HH + h) * 64 + svd) * 1024 + svp * 8;

    float mO[4] = {-1e30f, -1e30f, -1e30f, -1e30f};
    float lO[4] = {0.f, 0.f, 0.f, 0.f};
    f32x4 acc[4] = {};

    bf16* pw = Ps + wave * 640;
    const int kend = q0 + 64;
    const int qg0 = q0 + wave * 16 + 4 * g;

    for (int k0 = 0; k0 < kend; k0 += 32) {
        gload16(qkv + koff + (size_t)(k0 + skrow) * 3072, (char*)Ks + tid * 16);
        gload16(Vt + vtbase + k0, (char*)Vs + tid * 16);
        __syncthreads();

        const int cw = c & 7;
        bf16x8 kf00 = *(const bf16x8*)(Ks + c * 64        + ((g ^ cw) * 8));
        bf16x8 kf01 = *(const bf16x8*)(Ks + c * 64        + (((4 + g) ^ cw) * 8));
        bf16x8 kf10 = *(const bf16x8*)(Ks + (16 + c) * 64 + ((g ^ cw) * 8));
        bf16x8 kf11 = *(const bf16x8*)(Ks + (16 + c) * 64 + (((4 + g) ^ cw) * 8));
        f32x4 s0 = {}, s1 = {};
        s0 = __builtin_amdgcn_mfma_f32_16x16x32_bf16(qf0, kf00, s0, 0, 0, 0);
        s0 = __builtin_amdgcn_mfma_f32_16x16x32_bf16(qf1, kf01, s0, 0, 0, 0);
        s1 = __builtin_amdgcn_mfma_f32_16x16x32_bf16(qf0, kf10, s1, 0, 0, 0);
        s1 = __builtin_amdgcn_mfma_f32_16x16x32_bf16(qf1, kf11, s1, 0, 0, 0);

#pragma unroll
        for (int r = 0; r < 4; ++r) {
            float a  = s0[r] * 0.125f;
            float bv = s1[r] * 0.125f;
            int qg = qg0 + r;
            if (k0 + c > qg)      a  = -1e30f;
            if (k0 + 16 + c > qg) bv = -1e30f;
            float mt = fmaxf(a, bv);
            mt = fmaxf(mt, __shfl_xor(mt, 1));
            mt = fmaxf(mt, __shfl_xor(mt, 2));
            mt = fmaxf(mt, __shfl_xor(mt, 4));
            mt = fmaxf(mt, __shfl_xor(mt, 8));
            float mn = fmaxf(mO[r], mt);
            float sc = __expf(mO[r] - mn);
            mO[r] = mn;
            float e0 = __expf(a - mn), e1 = __expf(bv - mn);
            float rs = e0 + e1;
            rs += __shfl_xor(rs, 1);
            rs += __shfl_xor(rs, 2);
            rs += __shfl_xor(rs, 4);
            rs += __shfl_xor(rs, 8);
            lO[r] = lO[r] * sc + rs;
            acc[0][r] *= sc; acc[1][r] *= sc; acc[2][r] *= sc; acc[3][r] *= sc;
            pw[(4 * g + r) * 40 + c]      = (bf16)e0;
            pw[(4 * g + r) * 40 + 16 + c] = (bf16)e1;
        }

        bf16x8 pf = *(const bf16x8*)(pw + c * 40 + g * 8);
#pragma unroll
        for (int jb = 0; jb < 4; ++jb) {
            int d = jb * 16 + c;
            int swd = (d ^ (d >> 2)) & 3;
            bf16x8 vf = *(const bf16x8*)(Vs + d * 32 + ((g ^ swd) * 8));
            acc[jb] = __builtin_amdgcn_mfma_f32_16x16x32_bf16(pf, vf, acc[jb], 0, 0, 0);
        }
        __syncthreads();
    }

#pragma unroll
    for (int r = 0; r < 4; ++r) {
        float invl = 1.0f / lO[r];
        size_t orow = (size_t)(b * TT + qg0 + r) * DD + h * 64;
#pragma unroll
        for (int jb = 0; jb < 4; ++jb)
            y[orow + jb * 16 + c] = (bf16)(acc[jb][r] * invl);
    }
}

// ---------------- host ----------------
extern "C" void kernel_launch(void* const* d_in, const int* in_sizes, int n_in,
                              void* d_out, int out_size, void* d_ws, size_t ws_size,
                              hipStream_t stream) {
    const int*   idx     = (const int*)d_in[0];
    const float* tok_emb = (const float*)d_in[1];
    const float* pos_emb = (const float*)d_in[2];
    const float* ln1_g   = (const float*)d_in[3];
    const float* ln1_b   = (const float*)d_in[4];
    const float* qkv_w   = (const float*)d_in[5];
    const float* proj_w  = (const float*)d_in[6];
    const float* ln2_g   = (const float*)d_in[7];
    const float* ln2_b   = (const float*)d_in[8];
    const float* mlp_w1  = (const float*)d_in[9];
    const float* mlp_b1  = (const float*)d_in[10];
    const float* mlp_w2  = (const float*)d_in[11];
    const float* mlp_b2  = (const float*)d_in[12];
    const float* lnf_g   = (const float*)d_in[13];
    const float* lnf_b   = (const float*)d_in[14];
    const float* head_w  = (const float*)d_in[15];
    float* out = (float*)d_out;

    char* ws = (char*)d_ws;
    float* x      = (float*)ws;
    bf16*  qkv_bf = (bf16*)(ws + (16ull << 20));
    bf16*  Vt     = (bf16*)(ws + (40ull << 20));
    bf16*  h_bf   = (bf16*)(ws + (48ull << 20));
    bf16*  y_bf   = (bf16*)(ws + (56ull << 20));
    bf16*  ff_bf  = (bf16*)(ws + (64ull << 20));
    bf16*  wbuf   = (bf16*)(ws + (96ull << 20));
    bf16*  hw_bf  = (bf16*)(ws + (56ull << 20));

    embed_k<<<BT, 256, 0, stream>>>(idx, tok_emb, pos_emb, x);

    for (int l = 0; l < LL; ++l) {
        layernorm_k<<<BT, 256, 0, stream>>>(x, h_bf, ln1_g + (size_t)l * DD, ln1_b + (size_t)l * DD);
        cvt_bf16_k<<<2048, 256, 0, stream>>>(qkv_w + (size_t)l * 3 * DD * DD, wbuf, (long)3 * DD * DD);
        gemm_big<false, false, true><<<(BT / 256) * (3 * DD / 128), 512, 0, stream>>>(
            h_bf, wbuf, nullptr, qkv_bf, BT, 3 * DD, DD);
        vprep_k<<<2048, 256, 0, stream>>>(qkv_bf, Vt);
        fattn_k<<<dim3(TT / 64, HH, BB), 256, 0, stream>>>(qkv_bf, Vt, y_bf);
        cvt_bf16_k<<<2048, 256, 0, stream>>>(proj_w + (size_t)l * DD * DD, wbuf, (long)DD * DD);
        gemm_mfma<true, false, false, false><<<(BT / 128) * (DD / 128), 256, 0, stream>>>(
            y_bf, wbuf, nullptr, x, BT, DD, DD);
        layernorm_k<<<BT, 256, 0, stream>>>(x, h_bf, ln2_g + (size_t)l * DD, ln2_b + (size_t)l * DD);
        cvt_bf16_k<<<2048, 256, 0, stream>>>(mlp_w1 + (size_t)l * FFD * DD, wbuf, (long)FFD * DD);
        gemm_big<true, true, true><<<(BT / 256) * (FFD / 128), 512, 0, stream>>>(
            h_bf, wbuf, mlp_b1 + (size_t)l * FFD, ff_bf, BT, FFD, DD);
        cvt_bf16_k<<<2048, 256, 0, stream>>>(mlp_w2 + (size_t)l * DD * FFD, wbuf, (long)DD * FFD);
        gemm_mfma<true, true, false, false><<<(BT / 128) * (DD / 128), 256, 0, stream>>>(
            ff_bf, wbuf, mlp_b2 + (size_t)l * DD, x, BT, DD, FFD);
    }

    layernorm_k<<<BT, 256, 0, stream>>>(x, h_bf, lnf_g, lnf_b);
    cvt_bf16_k<<<4096, 256, 0, stream>>>(head_w, hw_bf, (long)VV * DD);
    gemm_big<false, false, false><<<(BT / 256) * (VV / 128), 512, 0, stream>>>(
        h_bf, hw_bf, nullptr, out, BT, VV, DD);
}

// Round 7
// 2724.195 us; speedup vs baseline: 1.0389x; 1.0056x over previous
//
#include <hip/hip_runtime.h>
#include <hip/hip_bf16.h>
#include <math.h>

#define BB 4
#define TT 1024
#define DD 1024
#define HH 16
#define HDIM 64
#define FFD 4096
#define VV 32000
#define LL 6
#define BT (BB * TT)

typedef __bf16 bf16;
typedef bf16 bf16x8 __attribute__((ext_vector_type(8)));
typedef bf16 bf16x4 __attribute__((ext_vector_type(4)));
typedef float f32x4 __attribute__((ext_vector_type(4)));

__device__ __forceinline__ void gload16(const void* g, void* l) {
    __builtin_amdgcn_global_load_lds((__attribute__((address_space(1))) unsigned int*)(g),
                                     (__attribute__((address_space(3))) unsigned int*)(l),
                                     16, 0, 0);
}

// ---------------- embedding ----------------
__global__ __launch_bounds__(256) void embed_k(const int* __restrict__ idx,
                                               const float* __restrict__ tok,
                                               const float* __restrict__ pos,
                                               float* __restrict__ x) {
    int row = blockIdx.x;
    int tid = threadIdx.x;
    int t = row & (TT - 1);
    int token = idx[row];
    float4 a = *(const float4*)(tok + (size_t)token * DD + tid * 4);
    float4 p = *(const float4*)(pos + (size_t)t * DD + tid * 4);
    *(float4*)(x + (size_t)row * DD + tid * 4) =
        make_float4(a.x + p.x, a.y + p.y, a.z + p.z, a.w + p.w);
}

// ---------------- f32 -> bf16 conversion (weights) ----------------
__global__ __launch_bounds__(256) void cvt_bf16_k(const float* __restrict__ in,
                                                  bf16* __restrict__ out, long n) {
    long i0 = ((long)blockIdx.x * 256 + threadIdx.x) * 8;
    long stride = (long)gridDim.x * 256 * 8;
    for (long i = i0; i < n; i += stride) {
        float4 v0 = *(const float4*)(in + i);
        float4 v1 = *(const float4*)(in + i + 4);
        bf16x8 o;
        o[0] = (bf16)v0.x; o[1] = (bf16)v0.y; o[2] = (bf16)v0.z; o[3] = (bf16)v0.w;
        o[4] = (bf16)v1.x; o[5] = (bf16)v1.y; o[6] = (bf16)v1.z; o[7] = (bf16)v1.w;
        *(bf16x8*)(out + i) = o;
    }
}

// ---------------- layernorm: f32 in, bf16 out ----------------
__global__ __launch_bounds__(256) void layernorm_k(const float* __restrict__ in,
                                                   bf16* __restrict__ out,
                                                   const float* __restrict__ g,
                                                   const float* __restrict__ b) {
    __shared__ float red[256];
    int row = blockIdx.x;
    int tid = threadIdx.x;
    const float* ip = in + (size_t)row * DD;
    float4 v = *(const float4*)(ip + tid * 4);

    float s = v.x + v.y + v.z + v.w;
    red[tid] = s; __syncthreads();
    for (int st = 128; st > 0; st >>= 1) { if (tid < st) red[tid] += red[tid + st]; __syncthreads(); }
    float mu = red[0] * (1.0f / DD);
    __syncthreads();

    float d0 = v.x - mu, d1 = v.y - mu, d2 = v.z - mu, d3 = v.w - mu;
    red[tid] = d0 * d0 + d1 * d1 + d2 * d2 + d3 * d3; __syncthreads();
    for (int st = 128; st > 0; st >>= 1) { if (tid < st) red[tid] += red[tid + st]; __syncthreads(); }
    float var = red[0] * (1.0f / DD);
    float rs = rsqrtf(var + 1e-5f);

    float4 gv = *(const float4*)(g + tid * 4);
    float4 bv = *(const float4*)(b + tid * 4);
    bf16x4 o;
    o[0] = (bf16)(d0 * rs * gv.x + bv.x);
    o[1] = (bf16)(d1 * rs * gv.y + bv.y);
    o[2] = (bf16)(d2 * rs * gv.z + bv.z);
    o[3] = (bf16)(d3 * rs * gv.w + bv.w);
    *(bf16x4*)(out + (size_t)row * DD + tid * 4) = o;
}

// ======== 256x256 GEMM: BK=32, 512 thr (2Mx4N waves, 128x64/wave), 3-buf ========
// C[M,N] = A[M,K] * W[N,K]^T ; counted vmcnt(8/4/0), XOR-swizzled LDS (64B rows,
// key(r) = (r&3)^((r>>2)&3)), setprio MFMA clusters, no mid-loop drain.
template <bool BIAS, bool GELU, bool OBF>
__global__ __launch_bounds__(512, 2) void gemm_256(const bf16* __restrict__ A,
                                                   const bf16* __restrict__ W,
                                                   const float* __restrict__ bias,
                                                   void* __restrict__ Cv,
                                                   int M, int N, int K) {
    __shared__ char lds[3 * 32768];     // per buf: A [256][32] @0, B @16384
    const int tid = threadIdx.x;
    const int lane = tid & 63, wave = tid >> 6;
    const int c = lane & 15, g = lane >> 4;

    const int nm = M >> 8;
    const int nwg = gridDim.x;
    const int wgid = (blockIdx.x & 7) * (nwg >> 3) + (blockIdx.x >> 3);
    const int m0 = (wgid % nm) * 256, n0 = (wgid / nm) * 256;

    const int wm = wave >> 2, wn = wave & 3;   // 2 x 4 waves, 128x64 each

    // staging map: thread -> row sr (+128 round 2), physical chunk tid&3,
    // fetches logical chunk lq = (tid&3) ^ key(sr)
    const int sr = tid >> 2;
    const int key_s = (sr & 3) ^ ((sr >> 2) & 3);
    const int lq = (tid & 3) ^ key_s;
    const size_t aoff = (size_t)(m0 + sr) * K + lq * 8;
    const size_t boff = (size_t)(n0 + sr) * K + lq * 8;
    const size_t K128 = (size_t)128 * K;

    // read offsets: row R reads logical chunk g at physical (g ^ key(R&15))
    const int key = (c & 3) ^ ((c >> 2) & 3);
    const int aRow = (wm * 128 + c) * 64 + ((g ^ key) * 16);
    const int bRow = 16384 + (wn * 64 + c) * 64 + ((g ^ key) * 16);

    f32x4 acc[8][4] = {};
    const int NT = K >> 5;

#define STG(t2, buf)                                                          \
    {                                                                         \
        const size_t kof = (size_t)(t2) * 32;                                 \
        const bf16* As_ = A + aoff + kof;                                     \
        char* dA = lds + (buf) * 32768 + tid * 16;                            \
        gload16(As_,        dA);                                              \
        gload16(As_ + K128, dA + 8192);                                       \
        const bf16* Bs_ = W + boff + kof;                                     \
        gload16(Bs_,        dA + 16384);                                      \
        gload16(Bs_ + K128, dA + 24576);                                      \
    }

    STG(0, 0);
    STG(1, 1);

    for (int t = 0; t < NT; ++t) {
        __builtin_amdgcn_s_barrier();          // prev occupant of (t+2)%3 fully read
        if (t + 2 < NT) {
            STG(t + 2, (t + 2) % 3);
            asm volatile("s_waitcnt vmcnt(8)" ::: "memory");   // tile t resident
        } else if (t + 1 < NT) {
            asm volatile("s_waitcnt vmcnt(4)" ::: "memory");
        } else {
            asm volatile("s_waitcnt vmcnt(0)" ::: "memory");
        }
        __builtin_amdgcn_sched_barrier(0);
        __builtin_amdgcn_s_barrier();

        const char* bp = lds + (t % 3) * 32768;
        bf16x8 bv[4];
#pragma unroll
        for (int fj = 0; fj < 4; ++fj) bv[fj] = *(const bf16x8*)(bp + bRow + fj * 1024);
        {   // phase 0: m-frags 0..3
            bf16x8 av[4];
#pragma unroll
            for (int fi = 0; fi < 4; ++fi) av[fi] = *(const bf16x8*)(bp + aRow + fi * 1024);
            __builtin_amdgcn_s_setprio(1);
#pragma unroll
            for (int fi = 0; fi < 4; ++fi)
#pragma unroll
                for (int fj = 0; fj < 4; ++fj)
                    acc[fi][fj] = __builtin_amdgcn_mfma_f32_16x16x32_bf16(av[fi], bv[fj], acc[fi][fj], 0, 0, 0);
            __builtin_amdgcn_s_setprio(0);
        }
        {   // phase 1: m-frags 4..7
            bf16x8 av[4];
#pragma unroll
            for (int fi = 0; fi < 4; ++fi) av[fi] = *(const bf16x8*)(bp + aRow + (fi + 4) * 1024);
            __builtin_amdgcn_s_setprio(1);
#pragma unroll
            for (int fi = 0; fi < 4; ++fi)
#pragma unroll
                for (int fj = 0; fj < 4; ++fj)
                    acc[fi + 4][fj] = __builtin_amdgcn_mfma_f32_16x16x32_bf16(av[fi], bv[fj], acc[fi + 4][fj], 0, 0, 0);
            __builtin_amdgcn_s_setprio(0);
        }
    }
#undef STG

    const int orow  = m0 + wm * 128 + g * 4;
    const int ocol0 = n0 + wn * 64 + c;
#pragma unroll
    for (int fj = 0; fj < 4; ++fj) {
        const int col = ocol0 + fj * 16;
        float bs = 0.f;
        if (BIAS) bs = bias[col];
#pragma unroll
        for (int fi = 0; fi < 8; ++fi) {
#pragma unroll
            for (int r = 0; r < 4; ++r) {
                int row = orow + fi * 16 + r;
                float v = acc[fi][fj][r] + bs;
                if (GELU) v = 0.5f * v * (1.0f + erff(v * 0.70710678118654752f));
                if (OBF) ((bf16*)Cv)[(size_t)row * N + col] = (bf16)v;
                else     ((float*)Cv)[(size_t)row * N + col] = v;
            }
        }
    }
}

// ---------------- 128x128 MFMA GEMM (N=1024 shapes) ----------------
template <bool ADD, bool BIAS, bool GELU, bool OBF>
__global__ __launch_bounds__(256) void gemm_mfma(const bf16* __restrict__ A,
                                                 const bf16* __restrict__ W,
                                                 const float* __restrict__ bias,
                                                 void* __restrict__ Cv,
                                                 int M, int N, int K) {
    __shared__ bf16 As[128 * 32];
    __shared__ bf16 Ws[128 * 32];
    const int tid  = threadIdx.x;
    const int wave = tid >> 6, lane = tid & 63;

    const int nm = M >> 7;
    const int nwg = gridDim.x;
    const int wgid = (blockIdx.x & 7) * (nwg >> 3) + (blockIdx.x >> 3);
    const int m0 = (wgid % nm) * 128, n0 = (wgid / nm) * 128;

    const int wm = (wave >> 1) * 64, wn = (wave & 1) * 64;

    const int srow = wave * 16 + (lane >> 2);
    const int sk   = (lane & 3) * 8;
    const bf16* Ag = A + (size_t)(m0 + srow) * K + sk;
    const bf16* Wg = W + (size_t)(n0 + srow) * K + sk;
    char* lA = (char*)As + wave * 1024;
    char* lW = (char*)Ws + wave * 1024;

    const int rl = lane & 15, kg = lane >> 4;
    const bf16* Ard = As + (size_t)(wm + rl) * 32 + kg * 8;
    const bf16* Wrd = Ws + (size_t)(wn + rl) * 32 + kg * 8;

    f32x4 acc[4][4] = {};

    for (int k0 = 0; k0 < K; k0 += 32) {
        gload16(Ag + k0,                   lA);
        gload16(Ag + k0 + (size_t)64 * K,  lA + 4096);
        gload16(Wg + k0,                   lW);
        gload16(Wg + k0 + (size_t)64 * K,  lW + 4096);
        __syncthreads();
        bf16x8 a[4], b[4];
#pragma unroll
        for (int i = 0; i < 4; ++i) a[i] = *(const bf16x8*)(Ard + i * 16 * 32);
#pragma unroll
        for (int j = 0; j < 4; ++j) b[j] = *(const bf16x8*)(Wrd + j * 16 * 32);
#pragma unroll
        for (int i = 0; i < 4; ++i)
#pragma unroll
            for (int j = 0; j < 4; ++j)
                acc[i][j] = __builtin_amdgcn_mfma_f32_16x16x32_bf16(a[i], b[j], acc[i][j], 0, 0, 0);
        __syncthreads();
    }

    const int orow  = m0 + wm + (lane >> 4) * 4;
    const int ocol0 = n0 + wn + (lane & 15);
#pragma unroll
    for (int j = 0; j < 4; ++j) {
        const int col = ocol0 + j * 16;
        float bs = 0.f;
        if (BIAS) bs = bias[col];
#pragma unroll
        for (int i = 0; i < 4; ++i) {
#pragma unroll
            for (int r = 0; r < 4; ++r) {
                int row = orow + i * 16 + r;
                float v = acc[i][j][r] + bs;
                if (GELU) v = 0.5f * v * (1.0f + erff(v * 0.70710678118654752f));
                if (OBF) {
                    ((bf16*)Cv)[(size_t)row * N + col] = (bf16)v;
                } else {
                    float* p = (float*)Cv + (size_t)row * N + col;
                    if (ADD) *p += v; else *p = v;
                }
            }
        }
    }
}

// ---------------- V transpose+swizzle prep ----------------
__global__ __launch_bounds__(256) void vprep_k(const bf16* __restrict__ qkv,
                                               bf16* __restrict__ Vt) {
    int tid = blockIdx.x * 256 + threadIdx.x;
    int q  = tid & 127;
    int d  = (tid >> 7) & 63;
    int bh = tid >> 13;
    int b = bh >> 4, h = bh & 15;
    int sw = (d ^ (d >> 2)) & 3;
    int srcc = (q & ~3) | ((q & 3) ^ sw);
    const bf16* src = qkv + ((size_t)(b * TT + srcc * 8)) * 3072 + 2048 + h * 64 + d;
    bf16x8 v;
#pragma unroll
    for (int i = 0; i < 8; ++i) v[i] = src[(size_t)i * 3072];
    *(bf16x8*)(Vt + ((size_t)bh * 64 + d) * 1024 + q * 8) = v;
}

// ---------------- flash attention ----------------
__global__ __launch_bounds__(256) void fattn_k(const bf16* __restrict__ qkv,
                                               const bf16* __restrict__ Vt,
                                               bf16* __restrict__ y) {
    __shared__ bf16 Ks[32 * 64];
    __shared__ bf16 Vs[64 * 32];
    __shared__ bf16 Ps[4 * 640];
    const int tid = threadIdx.x, lane = tid & 63, wave = tid >> 6;
    const int g = lane >> 4, c = lane & 15;
    const int q0 = blockIdx.x * 64;
    const int h = blockIdx.y, b = blockIdx.z;
    const size_t qbase = (size_t)b * TT * 3072;

    const int qrow = q0 + wave * 16 + c;
    const bf16* qp = qkv + qbase + (size_t)qrow * 3072 + h * 64;
    bf16x8 qf0 = *(const bf16x8*)(qp + g * 8);
    bf16x8 qf1 = *(const bf16x8*)(qp + 32 + g * 8);

    const int skrow = tid >> 3, skp = tid & 7;
    const size_t koff = qbase + 1024 + h * 64 + ((skp ^ (skrow & 7)) * 8);
    const int svd = tid >> 2, svp = tid & 3;
    const size_t vtbase = ((size_t)(b * HH + h) * 64 + svd) * 1024 + svp * 8;

    float mO[4] = {-1e30f, -1e30f, -1e30f, -1e30f};
    float lO[4] = {0.f, 0.f, 0.f, 0.f};
    f32x4 acc[4] = {};

    bf16* pw = Ps + wave * 640;
    const int kend = q0 + 64;
    const int qg0 = q0 + wave * 16 + 4 * g;

    for (int k0 = 0; k0 < kend; k0 += 32) {
        gload16(qkv + koff + (size_t)(k0 + skrow) * 3072, (char*)Ks + tid * 16);
        gload16(Vt + vtbase + k0, (char*)Vs + tid * 16);
        __syncthreads();

        const int cw = c & 7;
        bf16x8 kf00 = *(const bf16x8*)(Ks + c * 64        + ((g ^ cw) * 8));
        bf16x8 kf01 = *(const bf16x8*)(Ks + c * 64        + (((4 + g) ^ cw) * 8));
        bf16x8 kf10 = *(const bf16x8*)(Ks + (16 + c) * 64 + ((g ^ cw) * 8));
        bf16x8 kf11 = *(const bf16x8*)(Ks + (16 + c) * 64 + (((4 + g) ^ cw) * 8));
        f32x4 s0 = {}, s1 = {};
        s0 = __builtin_amdgcn_mfma_f32_16x16x32_bf16(qf0, kf00, s0, 0, 0, 0);
        s0 = __builtin_amdgcn_mfma_f32_16x16x32_bf16(qf1, kf01, s0, 0, 0, 0);
        s1 = __builtin_amdgcn_mfma_f32_16x16x32_bf16(qf0, kf10, s1, 0, 0, 0);
        s1 = __builtin_amdgcn_mfma_f32_16x16x32_bf16(qf1, kf11, s1, 0, 0, 0);

#pragma unroll
        for (int r = 0; r < 4; ++r) {
            float a  = s0[r] * 0.125f;
            float bv = s1[r] * 0.125f;
            int qg = qg0 + r;
            if (k0 + c > qg)      a  = -1e30f;
            if (k0 + 16 + c > qg) bv = -1e30f;
            float mt = fmaxf(a, bv);
            mt = fmaxf(mt, __shfl_xor(mt, 1));
            mt = fmaxf(mt, __shfl_xor(mt, 2));
            mt = fmaxf(mt, __shfl_xor(mt, 4));
            mt = fmaxf(mt, __shfl_xor(mt, 8));
            float mn = fmaxf(mO[r], mt);
            float sc = __expf(mO[r] - mn);
            mO[r] = mn;
            float e0 = __expf(a - mn), e1 = __expf(bv - mn);
            float rs = e0 + e1;
            rs += __shfl_xor(rs, 1);
            rs += __shfl_xor(rs, 2);
            rs += __shfl_xor(rs, 4);
            rs += __shfl_xor(rs, 8);
            lO[r] = lO[r] * sc + rs;
            acc[0][r] *= sc; acc[1][r] *= sc; acc[2][r] *= sc; acc[3][r] *= sc;
            pw[(4 * g + r) * 40 + c]      = (bf16)e0;
            pw[(4 * g + r) * 40 + 16 + c] = (bf16)e1;
        }

        bf16x8 pf = *(const bf16x8*)(pw + c * 40 + g * 8);
#pragma unroll
        for (int jb = 0; jb < 4; ++jb) {
            int d = jb * 16 + c;
            int swd = (d ^ (d >> 2)) & 3;
            bf16x8 vf = *(const bf16x8*)(Vs + d * 32 + ((g ^ swd) * 8));
            acc[jb] = __builtin_amdgcn_mfma_f32_16x16x32_bf16(pf, vf, acc[jb], 0, 0, 0);
        }
        __syncthreads();
    }

#pragma unroll
    for (int r = 0; r < 4; ++r) {
        float invl = 1.0f / lO[r];
        size_t orow = (size_t)(b * TT + qg0 + r) * DD + h * 64;
#pragma unroll
        for (int jb = 0; jb < 4; ++jb)
            y[orow + jb * 16 + c] = (bf16)(acc[jb][r] * invl);
    }
}

// ---------------- host ----------------
extern "C" void kernel_launch(void* const* d_in, const int* in_sizes, int n_in,
                              void* d_out, int out_size, void* d_ws, size_t ws_size,
                              hipStream_t stream) {
    const int*   idx     = (const int*)d_in[0];
    const float* tok_emb = (const float*)d_in[1];
    const float* pos_emb = (const float*)d_in[2];
    const float* ln1_g   = (const float*)d_in[3];
    const float* ln1_b   = (const float*)d_in[4];
    const float* qkv_w   = (const float*)d_in[5];
    const float* proj_w  = (const float*)d_in[6];
    const float* ln2_g   = (const float*)d_in[7];
    const float* ln2_b   = (const float*)d_in[8];
    const float* mlp_w1  = (const float*)d_in[9];
    const float* mlp_b1  = (const float*)d_in[10];
    const float* mlp_w2  = (const float*)d_in[11];
    const float* mlp_b2  = (const float*)d_in[12];
    const float* lnf_g   = (const float*)d_in[13];
    const float* lnf_b   = (const float*)d_in[14];
    const float* head_w  = (const float*)d_in[15];
    float* out = (float*)d_out;

    char* ws = (char*)d_ws;
    float* x      = (float*)ws;
    bf16*  qkv_bf = (bf16*)(ws + (16ull << 20));
    bf16*  Vt     = (bf16*)(ws + (40ull << 20));
    bf16*  h_bf   = (bf16*)(ws + (48ull << 20));
    bf16*  y_bf   = (bf16*)(ws + (56ull << 20));
    bf16*  ff_bf  = (bf16*)(ws + (64ull << 20));
    bf16*  wbuf   = (bf16*)(ws + (96ull << 20));
    bf16*  hw_bf  = (bf16*)(ws + (56ull << 20));

    embed_k<<<BT, 256, 0, stream>>>(idx, tok_emb, pos_emb, x);

    for (int l = 0; l < LL; ++l) {
        layernorm_k<<<BT, 256, 0, stream>>>(x, h_bf, ln1_g + (size_t)l * DD, ln1_b + (size_t)l * DD);
        cvt_bf16_k<<<2048, 256, 0, stream>>>(qkv_w + (size_t)l * 3 * DD * DD, wbuf, (long)3 * DD * DD);
        gemm_256<false, false, true><<<(BT / 256) * (3 * DD / 256), 512, 0, stream>>>(
            h_bf, wbuf, nullptr, qkv_bf, BT, 3 * DD, DD);
        vprep_k<<<2048, 256, 0, stream>>>(qkv_bf, Vt);
        fattn_k<<<dim3(TT / 64, HH, BB), 256, 0, stream>>>(qkv_bf, Vt, y_bf);
        cvt_bf16_k<<<2048, 256, 0, stream>>>(proj_w + (size_t)l * DD * DD, wbuf, (long)DD * DD);
        gemm_mfma<true, false, false, false><<<(BT / 128) * (DD / 128), 256, 0, stream>>>(
            y_bf, wbuf, nullptr, x, BT, DD, DD);
        layernorm_k<<<BT, 256, 0, stream>>>(x, h_bf, ln2_g + (size_t)l * DD, ln2_b + (size_t)l * DD);
        cvt_bf16_k<<<2048, 256, 0, stream>>>(mlp_w1 + (size_t)l * FFD * DD, wbuf, (long)FFD * DD);
        gemm_256<true, true, true><<<(BT / 256) * (FFD / 256), 512, 0, stream>>>(
            h_bf, wbuf, mlp_b1 + (size_t)l * FFD, ff_bf, BT, FFD, DD);
        cvt_bf16_k<<<2048, 256, 0, stream>>>(mlp_w2 + (size_t)l * DD * FFD, wbuf, (long)DD * FFD);
        gemm_mfma<true, true, false, false><<<(BT / 128) * (DD / 128), 256, 0, stream>>>(
            ff_bf, wbuf, mlp_b2 + (size_t)l * DD, x, BT, DD, FFD);
    }

    layernorm_k<<<BT, 256, 0, stream>>>(x, h_bf, lnf_g, lnf_b);
    cvt_bf16_k<<<4096, 256, 0, stream>>>(head_w, hw_bf, (long)VV * DD);
    gemm_256<false, false, false><<<(BT / 256) * (VV / 256), 512, 0, stream>>>(
        h_bf, hw_bf, nullptr, out, BT, VV, DD);
}

// Round 10
// 2635.706 us; speedup vs baseline: 1.0738x; 1.0336x over previous
//
#include <hip/hip_runtime.h>
#include <hip/hip_bf16.h>
#include <math.h>

#define BB 4
#define TT 1024
#define DD 1024
#define HH 16
#define HDIM 64
#define FFD 4096
#define VV 32000
#define LL 6
#define BT (BB * TT)

typedef __bf16 bf16;
typedef bf16 bf16x8 __attribute__((ext_vector_type(8)));
typedef bf16 bf16x4 __attribute__((ext_vector_type(4)));
typedef float f32x4 __attribute__((ext_vector_type(4)));

__device__ __forceinline__ void gload16(const void* g, void* l) {
    __builtin_amdgcn_global_load_lds((__attribute__((address_space(1))) unsigned int*)(g),
                                     (__attribute__((address_space(3))) unsigned int*)(l),
                                     16, 0, 0);
}

// ---------------- embedding ----------------
__global__ __launch_bounds__(256) void embed_k(const int* __restrict__ idx,
                                               const float* __restrict__ tok,
                                               const float* __restrict__ pos,
                                               float* __restrict__ x) {
    int row = blockIdx.x;
    int tid = threadIdx.x;
    int t = row & (TT - 1);
    int token = idx[row];
    float4 a = *(const float4*)(tok + (size_t)token * DD + tid * 4);
    float4 p = *(const float4*)(pos + (size_t)t * DD + tid * 4);
    *(float4*)(x + (size_t)row * DD + tid * 4) =
        make_float4(a.x + p.x, a.y + p.y, a.z + p.z, a.w + p.w);
}

// ---------------- f32 -> bf16 conversion (weights) ----------------
__global__ __launch_bounds__(256) void cvt_bf16_k(const float* __restrict__ in,
                                                  bf16* __restrict__ out, long n) {
    long i0 = ((long)blockIdx.x * 256 + threadIdx.x) * 8;
    long stride = (long)gridDim.x * 256 * 8;
    for (long i = i0; i < n; i += stride) {
        float4 v0 = *(const float4*)(in + i);
        float4 v1 = *(const float4*)(in + i + 4);
        bf16x8 o;
        o[0] = (bf16)v0.x; o[1] = (bf16)v0.y; o[2] = (bf16)v0.z; o[3] = (bf16)v0.w;
        o[4] = (bf16)v1.x; o[5] = (bf16)v1.y; o[6] = (bf16)v1.z; o[7] = (bf16)v1.w;
        *(bf16x8*)(out + i) = o;
    }
}

// ---------------- layernorm: f32 in, bf16 out ----------------
__global__ __launch_bounds__(256) void layernorm_k(const float* __restrict__ in,
                                                   bf16* __restrict__ out,
                                                   const float* __restrict__ g,
                                                   const float* __restrict__ b) {
    __shared__ float red[256];
    int row = blockIdx.x;
    int tid = threadIdx.x;
    const float* ip = in + (size_t)row * DD;
    float4 v = *(const float4*)(ip + tid * 4);

    float s = v.x + v.y + v.z + v.w;
    red[tid] = s; __syncthreads();
    for (int st = 128; st > 0; st >>= 1) { if (tid < st) red[tid] += red[tid + st]; __syncthreads(); }
    float mu = red[0] * (1.0f / DD);
    __syncthreads();

    float d0 = v.x - mu, d1 = v.y - mu, d2 = v.z - mu, d3 = v.w - mu;
    red[tid] = d0 * d0 + d1 * d1 + d2 * d2 + d3 * d3; __syncthreads();
    for (int st = 128; st > 0; st >>= 1) { if (tid < st) red[tid] += red[tid + st]; __syncthreads(); }
    float var = red[0] * (1.0f / DD);
    float rs = rsqrtf(var + 1e-5f);

    float4 gv = *(const float4*)(g + tid * 4);
    float4 bv = *(const float4*)(b + tid * 4);
    bf16x4 o;
    o[0] = (bf16)(d0 * rs * gv.x + bv.x);
    o[1] = (bf16)(d1 * rs * gv.y + bv.y);
    o[2] = (bf16)(d2 * rs * gv.z + bv.z);
    o[3] = (bf16)(d3 * rs * gv.w + bv.w);
    *(bf16x4*)(out + (size_t)row * DD + tid * 4) = o;
}

// ======== 256x256 GEMM, 8-phase schedule: BK=64, 512 thr (2Mx4N waves, 128x64/wave)
// LDS per buf: A [ks][256 rows][32 elems] 32KB @0, B same @32768; 2 bufs = 128KB.
// Per tile: 4 phases {ds_read, stage K-half H=P+5, bar, lgkm0, 16 MFMA, [vmcnt(6)], bar}.
// Swizzle: phys_chunk = log_chunk ^ ((row>>1)&3) — conflict-free b128; staged via
// pre-swizzled per-lane global src + linear LDS dest (both-sides rule).
template <bool BIAS, bool GELU, bool OBF>
__global__ __launch_bounds__(512, 2) void gemm_256(const bf16* __restrict__ A,
                                                   const bf16* __restrict__ W,
                                                   const float* __restrict__ bias,
                                                   void* __restrict__ Cv,
                                                   int M, int N, int K) {
    __shared__ char lds[2 * 65536];
    const int tid = threadIdx.x;
    const int lane = tid & 63, wave = tid >> 6;
    const int c = lane & 15, g = lane >> 4;

    const int nm = M >> 8;
    const int nwg = gridDim.x;
    const int wgid = (blockIdx.x & 7) * (nwg >> 3) + (blockIdx.x >> 3);
    const int m0 = (wgid % nm) * 256, n0 = (wgid / nm) * 256;
    const int wm = wave >> 2, wn = wave & 3;   // 2 x 4 waves, 128x64 each

    // staging: thread tid covers row (tid>>2)+i*128, phys chunk tid&3 -> logical
    // chunk lq = (tid&3) ^ key(row), key(row)=(row>>1)&3 = (tid>>3)&3 (both i)
    const int srow = tid >> 2;
    const int lq = (tid & 3) ^ ((tid >> 3) & 3);
    const bf16* Asrc = A + (size_t)(m0 + srow) * K + lq * 8;
    const bf16* Bsrc = W + (size_t)(n0 + srow) * K + lq * 8;
    const size_t K128 = (size_t)128 * K;

    // read offsets: row R, logical chunk g at phys g ^ ((c>>1)&3)  (R-dependence folds to c)
    const int key = (c >> 1) & 3;
    const int rdA = (wm * 128 + c) * 64 + ((g ^ key) * 16);          // + fi*1024 + ks*16384
    const int rdB = 32768 + (wn * 64 + c) * 64 + ((g ^ key) * 16);   // + fj*1024 + ks*16384

    f32x4 acc[8][4] = {};
    const int NT = K >> 6;
    const int NH = 4 * NT;

    // half H: tile H>>2, (H&1)=mat (0=A,1=B), (H>>1)&1=ks. Order: Aks0,Bks0,Aks1,Bks1.
#define STAGEH(H)                                                             \
    if ((H) < NH) {                                                           \
        const int t2_ = (H) >> 2, h_ = (H) & 3;                               \
        const bf16* s_ = ((h_ & 1) ? Bsrc : Asrc) + (size_t)t2_ * 64 + (h_ >> 1) * 32; \
        char* d_ = lds + (t2_ & 1) * 65536 + (h_ & 1) * 32768 + (h_ >> 1) * 16384 + tid * 16; \
        gload16(s_, d_);                                                      \
        gload16(s_ + K128, d_ + 8192);                                        \
    }

#define MFMA16(base)                                                          \
    __builtin_amdgcn_s_setprio(1);                                            \
    _Pragma("unroll")                                                         \
    for (int fi = 0; fi < 4; ++fi) {                                          \
        _Pragma("unroll")                                                     \
        for (int fj = 0; fj < 4; ++fj)                                        \
            acc[(base) + fi][fj] = __builtin_amdgcn_mfma_f32_16x16x32_bf16(   \
                bA[fi], bB[fj], acc[(base) + fi][fj], 0, 0, 0);               \
    }                                                                         \
    __builtin_amdgcn_s_setprio(0);

    // prologue: stage H=0..4 (tile0 complete + Aks0 of tile1), rendezvous
    STAGEH(0); STAGEH(1); STAGEH(2); STAGEH(3); STAGEH(4);
    asm volatile("s_waitcnt vmcnt(6)" ::: "memory");   // H0,H1 resident
    __builtin_amdgcn_sched_barrier(0);
    __builtin_amdgcn_s_barrier();
    __builtin_amdgcn_sched_barrier(0);

    for (int kt = 0; kt < NT; ++kt) {
        const char* bp = lds + (kt & 1) * 65536;
        bf16x8 bA[4], bB[4];
        // ---- phase 0: ks0, fi 0-3 ----
#pragma unroll
        for (int fj = 0; fj < 4; ++fj) bB[fj] = *(const bf16x8*)(bp + rdB + fj * 1024);
#pragma unroll
        for (int fi = 0; fi < 4; ++fi) bA[fi] = *(const bf16x8*)(bp + rdA + fi * 1024);
        STAGEH(4 * kt + 5);
        __builtin_amdgcn_s_barrier();
        asm volatile("s_waitcnt lgkmcnt(0)" ::: "memory");
        __builtin_amdgcn_sched_barrier(0);
        MFMA16(0)
        __builtin_amdgcn_s_barrier();
        __builtin_amdgcn_sched_barrier(0);
        // ---- phase 1: ks0, fi 4-7 ----
#pragma unroll
        for (int fi = 0; fi < 4; ++fi) bA[fi] = *(const bf16x8*)(bp + rdA + (4 + fi) * 1024);
        STAGEH(4 * kt + 6);
        __builtin_amdgcn_s_barrier();
        asm volatile("s_waitcnt lgkmcnt(0)" ::: "memory");
        __builtin_amdgcn_sched_barrier(0);
        MFMA16(4)
        if (kt + 1 < NT) { asm volatile("s_waitcnt vmcnt(6)" ::: "memory"); }
        else             { asm volatile("s_waitcnt vmcnt(0)" ::: "memory"); }
        __builtin_amdgcn_sched_barrier(0);
        __builtin_amdgcn_s_barrier();      // protects phase-2 reads (ks1 resident)
        __builtin_amdgcn_sched_barrier(0);
        // ---- phase 2: ks1, fi 0-3 ----
#pragma unroll
        for (int fj = 0; fj < 4; ++fj) bB[fj] = *(const bf16x8*)(bp + rdB + 16384 + fj * 1024);
#pragma unroll
        for (int fi = 0; fi < 4; ++fi) bA[fi] = *(const bf16x8*)(bp + rdA + 16384 + fi * 1024);
        STAGEH(4 * kt + 7);
        __builtin_amdgcn_s_barrier();
        asm volatile("s_waitcnt lgkmcnt(0)" ::: "memory");
        __builtin_amdgcn_sched_barrier(0);
        MFMA16(0)
        __builtin_amdgcn_s_barrier();
        __builtin_amdgcn_sched_barrier(0);
        // ---- phase 3: ks1, fi 4-7 ----
#pragma unroll
        for (int fi = 0; fi < 4; ++fi) bA[fi] = *(const bf16x8*)(bp + rdA + 16384 + (4 + fi) * 1024);
        STAGEH(4 * kt + 8);
        __builtin_amdgcn_s_barrier();
        asm volatile("s_waitcnt lgkmcnt(0)" ::: "memory");
        __builtin_amdgcn_sched_barrier(0);
        MFMA16(4)
        if (kt + 2 < NT)      { asm volatile("s_waitcnt vmcnt(6)" ::: "memory"); }
        else if (kt + 2 == NT){ asm volatile("s_waitcnt vmcnt(4)" ::: "memory"); }
        __builtin_amdgcn_sched_barrier(0);
        __builtin_amdgcn_s_barrier();      // protects next tile's phase-0 reads
        __builtin_amdgcn_sched_barrier(0);
    }
#undef STAGEH
#undef MFMA16

    const int orow  = m0 + wm * 128 + g * 4;
    const int ocol0 = n0 + wn * 64 + c;
#pragma unroll
    for (int fj = 0; fj < 4; ++fj) {
        const int col = ocol0 + fj * 16;
        float bs = 0.f;
        if (BIAS) bs = bias[col];
#pragma unroll
        for (int fi = 0; fi < 8; ++fi) {
#pragma unroll
            for (int r = 0; r < 4; ++r) {
                int row = orow + fi * 16 + r;
                float v = acc[fi][fj][r] + bs;
                if (GELU) v = 0.5f * v * (1.0f + erff(v * 0.70710678118654752f));
                if (OBF) ((bf16*)Cv)[(size_t)row * N + col] = (bf16)v;
                else     ((float*)Cv)[(size_t)row * N + col] = v;
            }
        }
    }
}

// ---------------- 128x128 MFMA GEMM (N=1024 shapes) ----------------
template <bool ADD, bool BIAS, bool GELU, bool OBF>
__global__ __launch_bounds__(256) void gemm_mfma(const bf16* __restrict__ A,
                                                 const bf16* __restrict__ W,
                                                 const float* __restrict__ bias,
                                                 void* __restrict__ Cv,
                                                 int M, int N, int K) {
    __shared__ bf16 As[128 * 32];
    __shared__ bf16 Ws[128 * 32];
    const int tid  = threadIdx.x;
    const int wave = tid >> 6, lane = tid & 63;

    const int nm = M >> 7;
    const int nwg = gridDim.x;
    const int wgid = (blockIdx.x & 7) * (nwg >> 3) + (blockIdx.x >> 3);
    const int m0 = (wgid % nm) * 128, n0 = (wgid / nm) * 128;

    const int wm = (wave >> 1) * 64, wn = (wave & 1) * 64;

    const int srow = wave * 16 + (lane >> 2);
    const int sk   = (lane & 3) * 8;
    const bf16* Ag = A + (size_t)(m0 + srow) * K + sk;
    const bf16* Wg = W + (size_t)(n0 + srow) * K + sk;
    char* lA = (char*)As + wave * 1024;
    char* lW = (char*)Ws + wave * 1024;

    const int rl = lane & 15, kg = lane >> 4;
    const bf16* Ard = As + (size_t)(wm + rl) * 32 + kg * 8;
    const bf16* Wrd = Ws + (size_t)(wn + rl) * 32 + kg * 8;

    f32x4 acc[4][4] = {};

    for (int k0 = 0; k0 < K; k0 += 32) {
        gload16(Ag + k0,                   lA);
        gload16(Ag + k0 + (size_t)64 * K,  lA + 4096);
        gload16(Wg + k0,                   lW);
        gload16(Wg + k0 + (size_t)64 * K,  lW + 4096);
        __syncthreads();
        bf16x8 a[4], b[4];
#pragma unroll
        for (int i = 0; i < 4; ++i) a[i] = *(const bf16x8*)(Ard + i * 16 * 32);
#pragma unroll
        for (int j = 0; j < 4; ++j) b[j] = *(const bf16x8*)(Wrd + j * 16 * 32);
#pragma unroll
        for (int i = 0; i < 4; ++i)
#pragma unroll
            for (int j = 0; j < 4; ++j)
                acc[i][j] = __builtin_amdgcn_mfma_f32_16x16x32_bf16(a[i], b[j], acc[i][j], 0, 0, 0);
        __syncthreads();
    }

    const int orow  = m0 + wm + (lane >> 4) * 4;
    const int ocol0 = n0 + wn + (lane & 15);
#pragma unroll
    for (int j = 0; j < 4; ++j) {
        const int col = ocol0 + j * 16;
        float bs = 0.f;
        if (BIAS) bs = bias[col];
#pragma unroll
        for (int i = 0; i < 4; ++i) {
#pragma unroll
            for (int r = 0; r < 4; ++r) {
                int row = orow + i * 16 + r;
                float v = acc[i][j][r] + bs;
                if (GELU) v = 0.5f * v * (1.0f + erff(v * 0.70710678118654752f));
                if (OBF) {
                    ((bf16*)Cv)[(size_t)row * N + col] = (bf16)v;
                } else {
                    float* p = (float*)Cv + (size_t)row * N + col;
                    if (ADD) *p += v; else *p = v;
                }
            }
        }
    }
}

// ---------------- V transpose+swizzle prep ----------------
__global__ __launch_bounds__(256) void vprep_k(const bf16* __restrict__ qkv,
                                               bf16* __restrict__ Vt) {
    int tid = blockIdx.x * 256 + threadIdx.x;
    int q  = tid & 127;
    int d  = (tid >> 7) & 63;
    int bh = tid >> 13;
    int b = bh >> 4, h = bh & 15;
    int sw = (d ^ (d >> 2)) & 3;
    int srcc = (q & ~3) | ((q & 3) ^ sw);
    const bf16* src = qkv + ((size_t)(b * TT + srcc * 8)) * 3072 + 2048 + h * 64 + d;
    bf16x8 v;
#pragma unroll
    for (int i = 0; i < 8; ++i) v[i] = src[(size_t)i * 3072];
    *(bf16x8*)(Vt + ((size_t)bh * 64 + d) * 1024 + q * 8) = v;
}

// ---------------- flash attention ----------------
__global__ __launch_bounds__(256) void fattn_k(const bf16* __restrict__ qkv,
                                               const bf16* __restrict__ Vt,
                                               bf16* __restrict__ y) {
    __shared__ bf16 Ks[32 * 64];
    __shared__ bf16 Vs[64 * 32];
    __shared__ bf16 Ps[4 * 640];
    const int tid = threadIdx.x, lane = tid & 63, wave = tid >> 6;
    const int g = lane >> 4, c = lane & 15;
    const int q0 = blockIdx.x * 64;
    const int h = blockIdx.y, b = blockIdx.z;
    const size_t qbase = (size_t)b * TT * 3072;

    const int qrow = q0 + wave * 16 + c;
    const bf16* qp = qkv + qbase + (size_t)qrow * 3072 + h * 64;
    bf16x8 qf0 = *(const bf16x8*)(qp + g * 8);
    bf16x8 qf1 = *(const bf16x8*)(qp + 32 + g * 8);

    const int skrow = tid >> 3, skp = tid & 7;
    const size_t koff = qbase + 1024 + h * 64 + ((skp ^ (skrow & 7)) * 8);
    const int svd = tid >> 2, svp = tid & 3;
    const size_t vtbase = ((size_t)(b * HH + h) * 64 + svd) * 1024 + svp * 8;

    float mO[4] = {-1e30f, -1e30f, -1e30f, -1e30f};
    float lO[4] = {0.f, 0.f, 0.f, 0.f};
    f32x4 acc[4] = {};

    bf16* pw = Ps + wave * 640;
    const int kend = q0 + 64;
    const int qg0 = q0 + wave * 16 + 4 * g;

    for (int k0 = 0; k0 < kend; k0 += 32) {
        gload16(qkv + koff + (size_t)(k0 + skrow) * 3072, (char*)Ks + tid * 16);
        gload16(Vt + vtbase + k0, (char*)Vs + tid * 16);
        __syncthreads();

        const int cw = c & 7;
        bf16x8 kf00 = *(const bf16x8*)(Ks + c * 64        + ((g ^ cw) * 8));
        bf16x8 kf01 = *(const bf16x8*)(Ks + c * 64        + (((4 + g) ^ cw) * 8));
        bf16x8 kf10 = *(const bf16x8*)(Ks + (16 + c) * 64 + ((g ^ cw) * 8));
        bf16x8 kf11 = *(const bf16x8*)(Ks + (16 + c) * 64 + (((4 + g) ^ cw) * 8));
        f32x4 s0 = {}, s1 = {};
        s0 = __builtin_amdgcn_mfma_f32_16x16x32_bf16(qf0, kf00, s0, 0, 0, 0);
        s0 = __builtin_amdgcn_mfma_f32_16x16x32_bf16(qf1, kf01, s0, 0, 0, 0);
        s1 = __builtin_amdgcn_mfma_f32_16x16x32_bf16(qf0, kf10, s1, 0, 0, 0);
        s1 = __builtin_amdgcn_mfma_f32_16x16x32_bf16(qf1, kf11, s1, 0, 0, 0);

#pragma unroll
        for (int r = 0; r < 4; ++r) {
            float a  = s0[r] * 0.125f;
            float bv = s1[r] * 0.125f;
            int qg = qg0 + r;
            if (k0 + c > qg)      a  = -1e30f;
            if (k0 + 16 + c > qg) bv = -1e30f;
            float mt = fmaxf(a, bv);
            mt = fmaxf(mt, __shfl_xor(mt, 1));
            mt = fmaxf(mt, __shfl_xor(mt, 2));
            mt = fmaxf(mt, __shfl_xor(mt, 4));
            mt = fmaxf(mt, __shfl_xor(mt, 8));
            float mn = fmaxf(mO[r], mt);
            float sc = __expf(mO[r] - mn);
            mO[r] = mn;
            float e0 = __expf(a - mn), e1 = __expf(bv - mn);
            float rs = e0 + e1;
            rs += __shfl_xor(rs, 1);
            rs += __shfl_xor(rs, 2);
            rs += __shfl_xor(rs, 4);
            rs += __shfl_xor(rs, 8);
            lO[r] = lO[r] * sc + rs;
            acc[0][r] *= sc; acc[1][r] *= sc; acc[2][r] *= sc; acc[3][r] *= sc;
            pw[(4 * g + r) * 40 + c]      = (bf16)e0;
            pw[(4 * g + r) * 40 + 16 + c] = (bf16)e1;
        }

        bf16x8 pf = *(const bf16x8*)(pw + c * 40 + g * 8);
#pragma unroll
        for (int jb = 0; jb < 4; ++jb) {
            int d = jb * 16 + c;
            int swd = (d ^ (d >> 2)) & 3;
            bf16x8 vf = *(const bf16x8*)(Vs + d * 32 + ((g ^ swd) * 8));
            acc[jb] = __builtin_amdgcn_mfma_f32_16x16x32_bf16(pf, vf, acc[jb], 0, 0, 0);
        }
        __syncthreads();
    }

#pragma unroll
    for (int r = 0; r < 4; ++r) {
        float invl = 1.0f / lO[r];
        size_t orow = (size_t)(b * TT + qg0 + r) * DD + h * 64;
#pragma unroll
        for (int jb = 0; jb < 4; ++jb)
            y[orow + jb * 16 + c] = (bf16)(acc[jb][r] * invl);
    }
}

// ---------------- host ----------------
extern "C" void kernel_launch(void* const* d_in, const int* in_sizes, int n_in,
                              void* d_out, int out_size, void* d_ws, size_t ws_size,
                              hipStream_t stream) {
    const int*   idx     = (const int*)d_in[0];
    const float* tok_emb = (const float*)d_in[1];
    const float* pos_emb = (const float*)d_in[2];
    const float* ln1_g   = (const float*)d_in[3];
    const float* ln1_b   = (const float*)d_in[4];
    const float* qkv_w   = (const float*)d_in[5];
    const float* proj_w  = (const float*)d_in[6];
    const float* ln2_g   = (const float*)d_in[7];
    const float* ln2_b   = (const float*)d_in[8];
    const float* mlp_w1  = (const float*)d_in[9];
    const float* mlp_b1  = (const float*)d_in[10];
    const float* mlp_w2  = (const float*)d_in[11];
    const float* mlp_b2  = (const float*)d_in[12];
    const float* lnf_g   = (const float*)d_in[13];
    const float* lnf_b   = (const float*)d_in[14];
    const float* head_w  = (const float*)d_in[15];
    float* out = (float*)d_out;

    char* ws = (char*)d_ws;
    float* x      = (float*)ws;
    bf16*  qkv_bf = (bf16*)(ws + (16ull << 20));
    bf16*  Vt     = (bf16*)(ws + (40ull << 20));
    bf16*  h_bf   = (bf16*)(ws + (48ull << 20));
    bf16*  y_bf   = (bf16*)(ws + (56ull << 20));
    bf16*  ff_bf  = (bf16*)(ws + (64ull << 20));
    bf16*  wbuf   = (bf16*)(ws + (96ull << 20));
    bf16*  hw_bf  = (bf16*)(ws + (56ull << 20));

    embed_k<<<BT, 256, 0, stream>>>(idx, tok_emb, pos_emb, x);

    for (int l = 0; l < LL; ++l) {
        layernorm_k<<<BT, 256, 0, stream>>>(x, h_bf, ln1_g + (size_t)l * DD, ln1_b + (size_t)l * DD);
        cvt_bf16_k<<<2048, 256, 0, stream>>>(qkv_w + (size_t)l * 3 * DD * DD, wbuf, (long)3 * DD * DD);
        gemm_256<false, false, true><<<(BT / 256) * (3 * DD / 256), 512, 0, stream>>>(
            h_bf, wbuf, nullptr, qkv_bf, BT, 3 * DD, DD);
        vprep_k<<<2048, 256, 0, stream>>>(qkv_bf, Vt);
        fattn_k<<<dim3(TT / 64, HH, BB), 256, 0, stream>>>(qkv_bf, Vt, y_bf);
        cvt_bf16_k<<<2048, 256, 0, stream>>>(proj_w + (size_t)l * DD * DD, wbuf, (long)DD * DD);
        gemm_mfma<true, false, false, false><<<(BT / 128) * (DD / 128), 256, 0, stream>>>(
            y_bf, wbuf, nullptr, x, BT, DD, DD);
        layernorm_k<<<BT, 256, 0, stream>>>(x, h_bf, ln2_g + (size_t)l * DD, ln2_b + (size_t)l * DD);
        cvt_bf16_k<<<2048, 256, 0, stream>>>(mlp_w1 + (size_t)l * FFD * DD, wbuf, (long)FFD * DD);
        gemm_256<true, true, true><<<(BT / 256) * (FFD / 256), 512, 0, stream>>>(
            h_bf, wbuf, mlp_b1 + (size_t)l * FFD, ff_bf, BT, FFD, DD);
        cvt_bf16_k<<<2048, 256, 0, stream>>>(mlp_w2 + (size_t)l * DD * FFD, wbuf, (long)DD * FFD);
        gemm_mfma<true, true, false, false><<<(BT / 128) * (DD / 128), 256, 0, stream>>>(
            ff_bf, wbuf, mlp_b2 + (size_t)l * DD, x, BT, DD, FFD);
    }

    layernorm_k<<<BT, 256, 0, stream>>>(x, h_bf, lnf_g, lnf_b);
    cvt_bf16_k<<<4096, 256, 0, stream>>>(head_w, hw_bf, (long)VV * DD);
    gemm_256<false, false, false><<<(BT / 256) * (VV / 256), 512, 0, stream>>>(
        h_bf, hw_bf, nullptr, out, BT, VV, DD);
}

// Round 12
// 2472.485 us; speedup vs baseline: 1.1447x; 1.0660x over previous
//
#include <hip/hip_runtime.h>
#include <hip/hip_bf16.h>
#include <math.h>

#define BB 4
#define TT 1024
#define DD 1024
#define HH 16
#define HDIM 64
#define FFD 4096
#define VV 32000
#define LL 6
#define BT (BB * TT)

typedef __bf16 bf16;
typedef bf16 bf16x8 __attribute__((ext_vector_type(8)));
typedef bf16 bf16x4 __attribute__((ext_vector_type(4)));
typedef float f32x4 __attribute__((ext_vector_type(4)));

__device__ __forceinline__ void gload16(const void* g, void* l) {
    __builtin_amdgcn_global_load_lds((__attribute__((address_space(1))) unsigned int*)(g),
                                     (__attribute__((address_space(3))) unsigned int*)(l),
                                     16, 0, 0);
}

// ---------------- embedding ----------------
__global__ __launch_bounds__(256) void embed_k(const int* __restrict__ idx,
                                               const float* __restrict__ tok,
                                               const float* __restrict__ pos,
                                               float* __restrict__ x) {
    int row = blockIdx.x;
    int tid = threadIdx.x;
    int t = row & (TT - 1);
    int token = idx[row];
    float4 a = *(const float4*)(tok + (size_t)token * DD + tid * 4);
    float4 p = *(const float4*)(pos + (size_t)t * DD + tid * 4);
    *(float4*)(x + (size_t)row * DD + tid * 4) =
        make_float4(a.x + p.x, a.y + p.y, a.z + p.z, a.w + p.w);
}

// ---------------- f32 -> bf16 conversion (weights) ----------------
__global__ __launch_bounds__(256) void cvt_bf16_k(const float* __restrict__ in,
                                                  bf16* __restrict__ out, long n) {
    long i0 = ((long)blockIdx.x * 256 + threadIdx.x) * 8;
    long stride = (long)gridDim.x * 256 * 8;
    for (long i = i0; i < n; i += stride) {
        float4 v0 = *(const float4*)(in + i);
        float4 v1 = *(const float4*)(in + i + 4);
        bf16x8 o;
        o[0] = (bf16)v0.x; o[1] = (bf16)v0.y; o[2] = (bf16)v0.z; o[3] = (bf16)v0.w;
        o[4] = (bf16)v1.x; o[5] = (bf16)v1.y; o[6] = (bf16)v1.z; o[7] = (bf16)v1.w;
        *(bf16x8*)(out + i) = o;
    }
}

// ---------------- layernorm: f32 in, bf16 out ----------------
__global__ __launch_bounds__(256) void layernorm_k(const float* __restrict__ in,
                                                   bf16* __restrict__ out,
                                                   const float* __restrict__ g,
                                                   const float* __restrict__ b) {
    __shared__ float red[256];
    int row = blockIdx.x;
    int tid = threadIdx.x;
    const float* ip = in + (size_t)row * DD;
    float4 v = *(const float4*)(ip + tid * 4);

    float s = v.x + v.y + v.z + v.w;
    red[tid] = s; __syncthreads();
    for (int st = 128; st > 0; st >>= 1) { if (tid < st) red[tid] += red[tid + st]; __syncthreads(); }
    float mu = red[0] * (1.0f / DD);
    __syncthreads();

    float d0 = v.x - mu, d1 = v.y - mu, d2 = v.z - mu, d3 = v.w - mu;
    red[tid] = d0 * d0 + d1 * d1 + d2 * d2 + d3 * d3; __syncthreads();
    for (int st = 128; st > 0; st >>= 1) { if (tid < st) red[tid] += red[tid + st]; __syncthreads(); }
    float var = red[0] * (1.0f / DD);
    float rs = rsqrtf(var + 1e-5f);

    float4 gv = *(const float4*)(g + tid * 4);
    float4 bv = *(const float4*)(b + tid * 4);
    bf16x4 o;
    o[0] = (bf16)(d0 * rs * gv.x + bv.x);
    o[1] = (bf16)(d1 * rs * gv.y + bv.y);
    o[2] = (bf16)(d2 * rs * gv.z + bv.z);
    o[3] = (bf16)(d3 * rs * gv.w + bv.w);
    *(bf16x4*)(out + (size_t)row * DD + tid * 4) = o;
}

// ======== 256x256 GEMM, 8-phase schedule (unchanged from round 10 win) ========
template <bool BIAS, bool GELU, bool OBF>
__global__ __launch_bounds__(512, 2) void gemm_256(const bf16* __restrict__ A,
                                                   const bf16* __restrict__ W,
                                                   const float* __restrict__ bias,
                                                   void* __restrict__ Cv,
                                                   int M, int N, int K) {
    __shared__ char lds[2 * 65536];
    const int tid = threadIdx.x;
    const int lane = tid & 63, wave = tid >> 6;
    const int c = lane & 15, g = lane >> 4;

    const int nm = M >> 8;
    const int nwg = gridDim.x;
    const int wgid = (blockIdx.x & 7) * (nwg >> 3) + (blockIdx.x >> 3);
    const int m0 = (wgid % nm) * 256, n0 = (wgid / nm) * 256;
    const int wm = wave >> 2, wn = wave & 3;   // 2 x 4 waves, 128x64 each

    const int srow = tid >> 2;
    const int lq = (tid & 3) ^ ((tid >> 3) & 3);
    const bf16* Asrc = A + (size_t)(m0 + srow) * K + lq * 8;
    const bf16* Bsrc = W + (size_t)(n0 + srow) * K + lq * 8;
    const size_t K128 = (size_t)128 * K;

    const int key = (c >> 1) & 3;
    const int rdA = (wm * 128 + c) * 64 + ((g ^ key) * 16);
    const int rdB = 32768 + (wn * 64 + c) * 64 + ((g ^ key) * 16);

    f32x4 acc[8][4] = {};
    const int NT = K >> 6;
    const int NH = 4 * NT;

#define STAGEH(H)                                                             \
    if ((H) < NH) {                                                           \
        const int t2_ = (H) >> 2, h_ = (H) & 3;                               \
        const bf16* s_ = ((h_ & 1) ? Bsrc : Asrc) + (size_t)t2_ * 64 + (h_ >> 1) * 32; \
        char* d_ = lds + (t2_ & 1) * 65536 + (h_ & 1) * 32768 + (h_ >> 1) * 16384 + tid * 16; \
        gload16(s_, d_);                                                      \
        gload16(s_ + K128, d_ + 8192);                                        \
    }

#define MFMA16(base)                                                          \
    __builtin_amdgcn_s_setprio(1);                                            \
    _Pragma("unroll")                                                         \
    for (int fi = 0; fi < 4; ++fi) {                                          \
        _Pragma("unroll")                                                     \
        for (int fj = 0; fj < 4; ++fj)                                        \
            acc[(base) + fi][fj] = __builtin_amdgcn_mfma_f32_16x16x32_bf16(   \
                bA[fi], bB[fj], acc[(base) + fi][fj], 0, 0, 0);               \
    }                                                                         \
    __builtin_amdgcn_s_setprio(0);

    STAGEH(0); STAGEH(1); STAGEH(2); STAGEH(3); STAGEH(4);
    asm volatile("s_waitcnt vmcnt(6)" ::: "memory");
    __builtin_amdgcn_sched_barrier(0);
    __builtin_amdgcn_s_barrier();
    __builtin_amdgcn_sched_barrier(0);

    for (int kt = 0; kt < NT; ++kt) {
        const char* bp = lds + (kt & 1) * 65536;
        bf16x8 bA[4], bB[4];
#pragma unroll
        for (int fj = 0; fj < 4; ++fj) bB[fj] = *(const bf16x8*)(bp + rdB + fj * 1024);
#pragma unroll
        for (int fi = 0; fi < 4; ++fi) bA[fi] = *(const bf16x8*)(bp + rdA + fi * 1024);
        STAGEH(4 * kt + 5);
        __builtin_amdgcn_s_barrier();
        asm volatile("s_waitcnt lgkmcnt(0)" ::: "memory");
        __builtin_amdgcn_sched_barrier(0);
        MFMA16(0)
        __builtin_amdgcn_s_barrier();
        __builtin_amdgcn_sched_barrier(0);
#pragma unroll
        for (int fi = 0; fi < 4; ++fi) bA[fi] = *(const bf16x8*)(bp + rdA + (4 + fi) * 1024);
        STAGEH(4 * kt + 6);
        __builtin_amdgcn_s_barrier();
        asm volatile("s_waitcnt lgkmcnt(0)" ::: "memory");
        __builtin_amdgcn_sched_barrier(0);
        MFMA16(4)
        if (kt + 1 < NT) { asm volatile("s_waitcnt vmcnt(6)" ::: "memory"); }
        else             { asm volatile("s_waitcnt vmcnt(0)" ::: "memory"); }
        __builtin_amdgcn_sched_barrier(0);
        __builtin_amdgcn_s_barrier();
        __builtin_amdgcn_sched_barrier(0);
#pragma unroll
        for (int fj = 0; fj < 4; ++fj) bB[fj] = *(const bf16x8*)(bp + rdB + 16384 + fj * 1024);
#pragma unroll
        for (int fi = 0; fi < 4; ++fi) bA[fi] = *(const bf16x8*)(bp + rdA + 16384 + fi * 1024);
        STAGEH(4 * kt + 7);
        __builtin_amdgcn_s_barrier();
        asm volatile("s_waitcnt lgkmcnt(0)" ::: "memory");
        __builtin_amdgcn_sched_barrier(0);
        MFMA16(0)
        __builtin_amdgcn_s_barrier();
        __builtin_amdgcn_sched_barrier(0);
#pragma unroll
        for (int fi = 0; fi < 4; ++fi) bA[fi] = *(const bf16x8*)(bp + rdA + 16384 + (4 + fi) * 1024);
        STAGEH(4 * kt + 8);
        __builtin_amdgcn_s_barrier();
        asm volatile("s_waitcnt lgkmcnt(0)" ::: "memory");
        __builtin_amdgcn_sched_barrier(0);
        MFMA16(4)
        if (kt + 2 < NT)      { asm volatile("s_waitcnt vmcnt(6)" ::: "memory"); }
        else if (kt + 2 == NT){ asm volatile("s_waitcnt vmcnt(4)" ::: "memory"); }
        __builtin_amdgcn_sched_barrier(0);
        __builtin_amdgcn_s_barrier();
        __builtin_amdgcn_sched_barrier(0);
    }
#undef STAGEH
#undef MFMA16

    const int orow  = m0 + wm * 128 + g * 4;
    const int ocol0 = n0 + wn * 64 + c;
#pragma unroll
    for (int fj = 0; fj < 4; ++fj) {
        const int col = ocol0 + fj * 16;
        float bs = 0.f;
        if (BIAS) bs = bias[col];
#pragma unroll
        for (int fi = 0; fi < 8; ++fi) {
#pragma unroll
            for (int r = 0; r < 4; ++r) {
                int row = orow + fi * 16 + r;
                float v = acc[fi][fj][r] + bs;
                if (GELU) v = 0.5f * v * (1.0f + erff(v * 0.70710678118654752f));
                if (OBF) ((bf16*)Cv)[(size_t)row * N + col] = (bf16)v;
                else     ((float*)Cv)[(size_t)row * N + col] = v;
            }
        }
    }
}

// ---------------- 128x128 MFMA GEMM (N=1024 shapes) ----------------
template <bool ADD, bool BIAS, bool GELU, bool OBF>
__global__ __launch_bounds__(256) void gemm_mfma(const bf16* __restrict__ A,
                                                 const bf16* __restrict__ W,
                                                 const float* __restrict__ bias,
                                                 void* __restrict__ Cv,
                                                 int M, int N, int K) {
    __shared__ bf16 As[128 * 32];
    __shared__ bf16 Ws[128 * 32];
    const int tid  = threadIdx.x;
    const int wave = tid >> 6, lane = tid & 63;

    const int nm = M >> 7;
    const int nwg = gridDim.x;
    const int wgid = (blockIdx.x & 7) * (nwg >> 3) + (blockIdx.x >> 3);
    const int m0 = (wgid % nm) * 128, n0 = (wgid / nm) * 128;

    const int wm = (wave >> 1) * 64, wn = (wave & 1) * 64;

    const int srow = wave * 16 + (lane >> 2);
    const int sk   = (lane & 3) * 8;
    const bf16* Ag = A + (size_t)(m0 + srow) * K + sk;
    const bf16* Wg = W + (size_t)(n0 + srow) * K + sk;
    char* lA = (char*)As + wave * 1024;
    char* lW = (char*)Ws + wave * 1024;

    const int rl = lane & 15, kg = lane >> 4;
    const bf16* Ard = As + (size_t)(wm + rl) * 32 + kg * 8;
    const bf16* Wrd = Ws + (size_t)(wn + rl) * 32 + kg * 8;

    f32x4 acc[4][4] = {};

    for (int k0 = 0; k0 < K; k0 += 32) {
        gload16(Ag + k0,                   lA);
        gload16(Ag + k0 + (size_t)64 * K,  lA + 4096);
        gload16(Wg + k0,                   lW);
        gload16(Wg + k0 + (size_t)64 * K,  lW + 4096);
        __syncthreads();
        bf16x8 a[4], b[4];
#pragma unroll
        for (int i = 0; i < 4; ++i) a[i] = *(const bf16x8*)(Ard + i * 16 * 32);
#pragma unroll
        for (int j = 0; j < 4; ++j) b[j] = *(const bf16x8*)(Wrd + j * 16 * 32);
#pragma unroll
        for (int i = 0; i < 4; ++i)
#pragma unroll
            for (int j = 0; j < 4; ++j)
                acc[i][j] = __builtin_amdgcn_mfma_f32_16x16x32_bf16(a[i], b[j], acc[i][j], 0, 0, 0);
        __syncthreads();
    }

    const int orow  = m0 + wm + (lane >> 4) * 4;
    const int ocol0 = n0 + wn + (lane & 15);
#pragma unroll
    for (int j = 0; j < 4; ++j) {
        const int col = ocol0 + j * 16;
        float bs = 0.f;
        if (BIAS) bs = bias[col];
#pragma unroll
        for (int i = 0; i < 4; ++i) {
#pragma unroll
            for (int r = 0; r < 4; ++r) {
                int row = orow + i * 16 + r;
                float v = acc[i][j][r] + bs;
                if (GELU) v = 0.5f * v * (1.0f + erff(v * 0.70710678118654752f));
                if (OBF) {
                    ((bf16*)Cv)[(size_t)row * N + col] = (bf16)v;
                } else {
                    float* p = (float*)Cv + (size_t)row * N + col;
                    if (ADD) *p += v; else *p = v;
                }
            }
        }
    }
}

// ---------------- V transpose prep: Vt[bh][d][t] = V[b][t][h*64+d] (plain) ----------------
__global__ __launch_bounds__(256) void vprep_k(const bf16* __restrict__ qkv,
                                               bf16* __restrict__ Vt) {
    int tid = blockIdx.x * 256 + threadIdx.x;
    int q  = tid & 127;          // t-chunk of 8
    int d  = (tid >> 7) & 63;
    int bh = tid >> 13;
    int b = bh >> 4, h = bh & 15;
    const bf16* src = qkv + ((size_t)(b * TT + q * 8)) * 3072 + 2048 + h * 64 + d;
    bf16x8 v;
#pragma unroll
    for (int i = 0; i < 8; ++i) v[i] = src[(size_t)i * 3072];
    *(bf16x8*)(Vt + ((size_t)bh * 64 + d) * 1024 + q * 8) = v;
}

// ---------------- flash attention v2: KVBLK=64, double-buffered, deferred l ----------------
// Ks[buf][64 k][64 d], Vs[buf][64 d][64 t]: rows 128B, chunk-XOR swizzle (^row&7),
// staged via pre-swizzled per-lane global src + linear LDS dest.
// Each thread stages rows (tid>>3) and (tid>>3)+32 of both K and V: 4 gloads/tile.
// Counted vmcnt(4) mid-loop; vmcnt(0) last tile only.
__global__ __launch_bounds__(256) void fattn_k(const bf16* __restrict__ qkv,
                                               const bf16* __restrict__ Vt,
                                               bf16* __restrict__ y) {
    __shared__ bf16 Ks[2][64 * 64];
    __shared__ bf16 Vs[2][64 * 64];
    __shared__ bf16 Ps[4][16 * 72];
    const int tid = threadIdx.x, lane = tid & 63, wave = tid >> 6;
    const int g = lane >> 4, c = lane & 15;
    const int q0 = blockIdx.x * 64;
    const int h = blockIdx.y, b = blockIdx.z;
    const size_t qbase = (size_t)b * TT * 3072;

    // Q fragments (A-frag rows = c)
    const int qrow = q0 + wave * 16 + c;
    const bf16* qp = qkv + qbase + (size_t)qrow * 3072 + h * 64;
    bf16x8 qf0 = *(const bf16x8*)(qp + g * 8);
    bf16x8 qf1 = *(const bf16x8*)(qp + 32 + g * 8);

    // staging: thread -> rows (tid>>3) and (tid>>3)+32; phys chunk tid&7,
    // logical chunk = phys ^ (row&7); (row+32)&7 == row&7 so same lq for both.
    const int srow = tid >> 3;
    const int lq = (tid & 7) ^ (srow & 7);
    const bf16* Ksrc = qkv + qbase + 1024 + h * 64 + (size_t)srow * 3072 + lq * 8;
    const bf16* Vsrc = Vt + ((size_t)(b * HH + h) * 64 + srow) * 1024 + lq * 8;

    float mO[4] = {-1e30f, -1e30f, -1e30f, -1e30f};
    float lO[4] = {0.f, 0.f, 0.f, 0.f};
    f32x4 acc[4] = {};

    bf16* pw = Ps[wave];
    const int ntiles = blockIdx.x + 1;
    const int qg0 = q0 + wave * 16 + 4 * g;
    const int cs = c & 7;

#define STAGE_KV(t_, buf_)                                                        \
    {                                                                             \
        const int kk_ = (t_) * 64;                                                \
        gload16(Ksrc + (size_t)kk_ * 3072,        (char*)Ks[buf_] + tid * 16);    \
        gload16(Ksrc + (size_t)(kk_ + 32) * 3072, (char*)Ks[buf_] + tid * 16 + 4096); \
        gload16(Vsrc + kk_,                       (char*)Vs[buf_] + tid * 16);    \
        gload16(Vsrc + 32 * 1024 + kk_,           (char*)Vs[buf_] + tid * 16 + 4096); \
    }

    // prologue: stage tile 0
    STAGE_KV(0, 0)

    for (int t = 0; t < ntiles; ++t) {
        const int k0 = t * 64;
        if (t + 1 < ntiles) {
            STAGE_KV(t + 1, (t + 1) & 1)
            asm volatile("s_waitcnt vmcnt(4)" ::: "memory");
        } else {
            asm volatile("s_waitcnt vmcnt(0)" ::: "memory");
        }
        __builtin_amdgcn_sched_barrier(0);
        __builtin_amdgcn_s_barrier();
        __builtin_amdgcn_sched_barrier(0);

        const bf16* kb = Ks[t & 1];
        const bf16* vb = Vs[t & 1];

        // QK^T: S[16q x 64k] in s[0..3] (k-col groups c+16j)
        f32x4 s[4] = {};
#pragma unroll
        for (int j = 0; j < 4; ++j) {
            const bf16* kr = kb + (16 * j + c) * 64;
            bf16x8 kf0 = *(const bf16x8*)(kr + ((g ^ cs) * 8));
            bf16x8 kf1 = *(const bf16x8*)(kr + (((4 + g) ^ cs) * 8));
            s[j] = __builtin_amdgcn_mfma_f32_16x16x32_bf16(qf0, kf0, s[j], 0, 0, 0);
            s[j] = __builtin_amdgcn_mfma_f32_16x16x32_bf16(qf1, kf1, s[j], 0, 0, 0);
        }

        // mask + per-row tile max
        float mt_[4];
        bool need = false;
#pragma unroll
        for (int r = 0; r < 4; ++r) {
            const int qg = qg0 + r;
            float a0 = s[0][r] * 0.125f, a1 = s[1][r] * 0.125f;
            float a2 = s[2][r] * 0.125f, a3 = s[3][r] * 0.125f;
            if (k0 + c > qg)      a0 = -1e30f;
            if (k0 + 16 + c > qg) a1 = -1e30f;
            if (k0 + 32 + c > qg) a2 = -1e30f;
            if (k0 + 48 + c > qg) a3 = -1e30f;
            s[0][r] = a0; s[1][r] = a1; s[2][r] = a2; s[3][r] = a3;
            float mt = fmaxf(fmaxf(a0, a1), fmaxf(a2, a3));
            mt = fmaxf(mt, __shfl_xor(mt, 1));
            mt = fmaxf(mt, __shfl_xor(mt, 2));
            mt = fmaxf(mt, __shfl_xor(mt, 4));
            mt = fmaxf(mt, __shfl_xor(mt, 8));
            mt_[r] = mt;
            need |= (mt > mO[r]);
        }
        if (__any(need)) {      // defer-max (THR=0, exact): skip rescale when max unchanged
#pragma unroll
            for (int r = 0; r < 4; ++r) {
                float mn = fmaxf(mO[r], mt_[r]);
                float sc = __expf(mO[r] - mn);
                mO[r] = mn;
                lO[r] *= sc;
                acc[0][r] *= sc; acc[1][r] *= sc; acc[2][r] *= sc; acc[3][r] *= sc;
            }
        }
#pragma unroll
        for (int r = 0; r < 4; ++r) {
            float e0 = __expf(s[0][r] - mO[r]);
            float e1 = __expf(s[1][r] - mO[r]);
            float e2 = __expf(s[2][r] - mO[r]);
            float e3 = __expf(s[3][r] - mO[r]);
            lO[r] += (e0 + e1) + (e2 + e3);   // per-lane partial; reduced once at end
            bf16* pr = pw + (4 * g + r) * 72;
            pr[c] = (bf16)e0; pr[16 + c] = (bf16)e1;
            pr[32 + c] = (bf16)e2; pr[48 + c] = (bf16)e3;
        }

        // PV: acc[jb] += P[,ks] . V
#pragma unroll
        for (int ks = 0; ks < 2; ++ks) {
            bf16x8 pf = *(const bf16x8*)(pw + c * 72 + ks * 32 + g * 8);
#pragma unroll
            for (int jb = 0; jb < 4; ++jb) {
                const int d = 16 * jb + c;
                bf16x8 vf = *(const bf16x8*)(vb + d * 64 + (((ks * 4 + g) ^ cs) * 8));
                acc[jb] = __builtin_amdgcn_mfma_f32_16x16x32_bf16(pf, vf, acc[jb], 0, 0, 0);
            }
        }
        __builtin_amdgcn_s_barrier();       // protect buffer reuse by next stage
        __builtin_amdgcn_sched_barrier(0);
    }
#undef STAGE_KV

    // final l reduce (once) + store
#pragma unroll
    for (int r = 0; r < 4; ++r) {
        float l = lO[r];
        l += __shfl_xor(l, 1);
        l += __shfl_xor(l, 2);
        l += __shfl_xor(l, 4);
        l += __shfl_xor(l, 8);
        float invl = 1.0f / l;
        size_t orow = (size_t)(b * TT + qg0 + r) * DD + h * 64;
#pragma unroll
        for (int jb = 0; jb < 4; ++jb)
            y[orow + jb * 16 + c] = (bf16)(acc[jb][r] * invl);
    }
}

// ---------------- host ----------------
extern "C" void kernel_launch(void* const* d_in, const int* in_sizes, int n_in,
                              void* d_out, int out_size, void* d_ws, size_t ws_size,
                              hipStream_t stream) {
    const int*   idx     = (const int*)d_in[0];
    const float* tok_emb = (const float*)d_in[1];
    const float* pos_emb = (const float*)d_in[2];
    const float* ln1_g   = (const float*)d_in[3];
    const float* ln1_b   = (const float*)d_in[4];
    const float* qkv_w   = (const float*)d_in[5];
    const float* proj_w  = (const float*)d_in[6];
    const float* ln2_g   = (const float*)d_in[7];
    const float* ln2_b   = (const float*)d_in[8];
    const float* mlp_w1  = (const float*)d_in[9];
    const float* mlp_b1  = (const float*)d_in[10];
    const float* mlp_w2  = (const float*)d_in[11];
    const float* mlp_b2  = (const float*)d_in[12];
    const float* lnf_g   = (const float*)d_in[13];
    const float* lnf_b   = (const float*)d_in[14];
    const float* head_w  = (const float*)d_in[15];
    float* out = (float*)d_out;

    char* ws = (char*)d_ws;
    float* x      = (float*)ws;
    bf16*  qkv_bf = (bf16*)(ws + (16ull << 20));
    bf16*  Vt     = (bf16*)(ws + (40ull << 20));
    bf16*  h_bf   = (bf16*)(ws + (48ull << 20));
    bf16*  y_bf   = (bf16*)(ws + (56ull << 20));
    bf16*  ff_bf  = (bf16*)(ws + (64ull << 20));
    bf16*  wbuf   = (bf16*)(ws + (96ull << 20));
    bf16*  hw_bf  = (bf16*)(ws + (56ull << 20));

    embed_k<<<BT, 256, 0, stream>>>(idx, tok_emb, pos_emb, x);

    for (int l = 0; l < LL; ++l) {
        layernorm_k<<<BT, 256, 0, stream>>>(x, h_bf, ln1_g + (size_t)l * DD, ln1_b + (size_t)l * DD);
        cvt_bf16_k<<<2048, 256, 0, stream>>>(qkv_w + (size_t)l * 3 * DD * DD, wbuf, (long)3 * DD * DD);
        gemm_256<false, false, true><<<(BT / 256) * (3 * DD / 256), 512, 0, stream>>>(
            h_bf, wbuf, nullptr, qkv_bf, BT, 3 * DD, DD);
        vprep_k<<<2048, 256, 0, stream>>>(qkv_bf, Vt);
        fattn_k<<<dim3(TT / 64, HH, BB), 256, 0, stream>>>(qkv_bf, Vt, y_bf);
        cvt_bf16_k<<<2048, 256, 0, stream>>>(proj_w + (size_t)l * DD * DD, wbuf, (long)DD * DD);
        gemm_mfma<true, false, false, false><<<(BT / 128) * (DD / 128), 256, 0, stream>>>(
            y_bf, wbuf, nullptr, x, BT, DD, DD);
        layernorm_k<<<BT, 256, 0, stream>>>(x, h_bf, ln2_g + (size_t)l * DD, ln2_b + (size_t)l * DD);
        cvt_bf16_k<<<2048, 256, 0, stream>>>(mlp_w1 + (size_t)l * FFD * DD, wbuf, (long)FFD * DD);
        gemm_256<true, true, true><<<(BT / 256) * (FFD / 256), 512, 0, stream>>>(
            h_bf, wbuf, mlp_b1 + (size_t)l * FFD, ff_bf, BT, FFD, DD);
        cvt_bf16_k<<<2048, 256, 0, stream>>>(mlp_w2 + (size_t)l * DD * FFD, wbuf, (long)DD * FFD);
        gemm_mfma<true, true, false, false><<<(BT / 128) * (DD / 128), 256, 0, stream>>>(
            ff_bf, wbuf, mlp_b2 + (size_t)l * DD, x, BT, DD, FFD);
    }

    layernorm_k<<<BT, 256, 0, stream>>>(x, h_bf, lnf_g, lnf_b);
    cvt_bf16_k<<<4096, 256, 0, stream>>>(head_w, hw_bf, (long)VV * DD);
    gemm_256<false, false, false><<<(BT / 256) * (VV / 256), 512, 0, stream>>>(
        h_bf, hw_bf, nullptr, out, BT, VV, DD);
}